// Round 9
// baseline (18000.494 us; speedup 1.0000x reference)
//
#include <hip/hip_runtime.h>

#define TT 100
#define HH 1024
#define H3 3072
#define NOUT 28

#define AGENT __HIP_MEMORY_SCOPE_AGENT
#define WGRP  __HIP_MEMORY_SCOPE_WORKGROUP
#define GB_CAP  (1u<<13)
#define LDS_CAP (1u<<20)
#define FL_CAP  (1u<<16)

__device__ __forceinline__ float frcp_(float x){ return __builtin_amdgcn_rcpf(x); }
__device__ __forceinline__ float fsig_(float x){ return frcp_(1.0f + __expf(-x)); }
__device__ __forceinline__ float ftanh_(float x){ return 1.0f - 2.0f*frcp_(__expf(2.0f*x) + 1.0f); }
__device__ __forceinline__ void wait_vm(){ asm volatile("s_waitcnt vmcnt(0)" ::: "memory"); }

__device__ __forceinline__ unsigned long long aload8(const unsigned long long* p){
    return __hip_atomic_load(p, __ATOMIC_RELAXED, AGENT);
}
__device__ __forceinline__ unsigned aload4(const int* p){
    return (unsigned)__hip_atomic_load(p, __ATOMIC_RELAXED, AGENT);
}

// grid barrier: 16 padded sub-counters per slot (slot stride = 256 ints), relaxed only.
// Cross-WG data travels via agent-scope atomics (round-4/8-proven); caps keep failure cheap.
__device__ __forceinline__ void gridbar(int* slot, int sub, int target){
    wait_vm();
    __syncthreads();
    if (threadIdx.x == 0){
        __hip_atomic_fetch_add(slot + sub*16, 1, __ATOMIC_RELAXED, AGENT);
        unsigned gy = 0; int s;
        do {
            s = 0;
            #pragma unroll
            for (int c=0;c<16;c++) s += __hip_atomic_load(slot + c*16, __ATOMIC_RELAXED, AGENT);
            if (s < target){ if (++gy > GB_CAP) break; __builtin_amdgcn_s_sleep(1); }
        } while (s < target);
    }
    __syncthreads();
}

// ---------------- init: zero control ints ----------------
__global__ void k_init(int* ib, int n){
    int g = blockIdx.x*256 + threadIdx.x;
    if (g < n) ib[g] = 0;
}

// ---------------- transpose U [1024][3072] -> Ut [3072][1024] ----------------
__global__ __launch_bounds__(256) void k_transpose(const float* __restrict__ U0,
                                                   const float* __restrict__ U1,
                                                   float* __restrict__ T0,
                                                   float* __restrict__ T1){
    const float* U = blockIdx.z ? U1 : U0;
    float*       T = blockIdx.z ? T1 : T0;
    __shared__ float tile[32][33];
    int tx = threadIdx.x & 31, ty = threadIdx.x >> 5;
    int j0 = blockIdx.x*32, k0 = blockIdx.y*32;
    #pragma unroll
    for (int q=0;q<4;q++){
        int kr = ty + q*8;
        tile[kr][tx] = U[(size_t)(k0+kr)*H3 + j0 + tx];
    }
    __syncthreads();
    #pragma unroll
    for (int q=0;q<4;q++){
        int jr = ty + q*8;
        T[(size_t)(j0+jr)*HH + k0 + tx] = tile[tx][jr];
    }
}

// ---------------- Edec[28][3072] = emb @ decW + decb[0] ----------------
__global__ __launch_bounds__(256) void k_edec(const float* __restrict__ emb,
                                              const float* __restrict__ W,
                                              const float* __restrict__ b0,
                                              float* __restrict__ E){
    int gid = blockIdx.x*256 + threadIdx.x;   // 28*3072 = 86016
    int v = gid / H3, j = gid - v*H3;
    float acc = b0[j];
    const float* er = emb + (size_t)v*HH;
    #pragma unroll 4
    for (int k=0;k<HH;k++) acc = fmaf(er[k], W[(size_t)k*H3 + j], acc);
    E[gid] = acc;
}

// ---------------- MXT[t][col][b] = (x2d @ encW + encb[0]) transposed ----------------
__global__ __launch_bounds__(256) void k_mxgemm(const float* __restrict__ A,
                                                const float* __restrict__ W,
                                                const float* __restrict__ b0,
                                                float* __restrict__ MXT){
    __shared__ float aT[32*68];
    __shared__ float bL[32*68];
    int tid = threadIdx.x;
    int row0 = blockIdx.y*64, col0 = blockIdx.x*64;
    int arow = tid>>2, acs = (tid&3)*4;
    int bk   = tid>>3, bcs = (tid&7)*4;
    int ty = tid>>4, tx = tid&15;
    float acc[4][4] = {};
    for (int kk=0; kk<HH; kk+=32){
        #pragma unroll
        for (int i=0;i<2;i++){
            int c = acs + i*16;
            float4 v = *(const float4*)(A + (size_t)(row0+arow)*HH + kk + c);
            aT[(c+0)*68 + arow] = v.x; aT[(c+1)*68 + arow] = v.y;
            aT[(c+2)*68 + arow] = v.z; aT[(c+3)*68 + arow] = v.w;
        }
        #pragma unroll
        for (int i=0;i<2;i++){
            int c = bcs + i*32;
            float4 v = *(const float4*)(W + (size_t)(kk+bk)*H3 + col0 + c);
            *(float4*)(bL + bk*68 + c) = v;
        }
        __syncthreads();
        #pragma unroll
        for (int k=0;k<32;k++){
            float4 a4 = *(const float4*)(aT + k*68 + ty*4);
            float4 b4 = *(const float4*)(bL + k*68 + tx*4);
            acc[0][0]=fmaf(a4.x,b4.x,acc[0][0]); acc[0][1]=fmaf(a4.x,b4.y,acc[0][1]);
            acc[0][2]=fmaf(a4.x,b4.z,acc[0][2]); acc[0][3]=fmaf(a4.x,b4.w,acc[0][3]);
            acc[1][0]=fmaf(a4.y,b4.x,acc[1][0]); acc[1][1]=fmaf(a4.y,b4.y,acc[1][1]);
            acc[1][2]=fmaf(a4.y,b4.z,acc[1][2]); acc[1][3]=fmaf(a4.y,b4.w,acc[1][3]);
            acc[2][0]=fmaf(a4.z,b4.x,acc[2][0]); acc[2][1]=fmaf(a4.z,b4.y,acc[2][1]);
            acc[2][2]=fmaf(a4.z,b4.z,acc[2][2]); acc[2][3]=fmaf(a4.z,b4.w,acc[2][3]);
            acc[3][0]=fmaf(a4.w,b4.x,acc[3][0]); acc[3][1]=fmaf(a4.w,b4.y,acc[3][1]);
            acc[3][2]=fmaf(a4.w,b4.z,acc[3][2]); acc[3][3]=fmaf(a4.w,b4.w,acc[3][3]);
        }
        __syncthreads();
    }
    float4 bb = *(const float4*)(b0 + col0 + tx*4);
    #pragma unroll
    for (int i=0;i<4;i++){
        int r = row0 + ty*4 + i;
        int bq = r / 100; int tq = r - bq*100;
        float v0 = acc[i][0] + bb.x, v1 = acc[i][1] + bb.y;
        float v2 = acc[i][2] + bb.z, v3 = acc[i][3] + bb.w;
        float* dst = MXT + ((size_t)tq*H3 + col0 + tx*4)*64 + bq;
        dst[0]   = v0; dst[64]  = v1; dst[128] = v2; dst[192] = v3;
    }
}

// ---------------- persistent encoder: 64 WGs x 512 thr, 8 waves x 2 units ----------------
__global__ __launch_bounds__(512) void k_enc(const float* __restrict__ MXT,
                                             const float* __restrict__ Ut,
                                             const float* __restrict__ b1,
                                             float* __restrict__ hpe,
                                             float* __restrict__ g_h,   // [2][1024][64]
                                             int* __restrict__ bar){
    __shared__ float hs[2][16384];
    int tid = threadIdx.x, lane = tid & 63, wg = blockIdx.x, sub = wg & 15;
    int cu0 = __builtin_amdgcn_readfirstlane(wg*16 + (tid>>6)*2);
    int cu1 = cu0 + 1;
    const float* Uz0 = Ut + (size_t)cu0*HH;
    const float* Ur0 = Uz0 + (size_t)HH*HH;
    const float* Uh0 = Ur0 + (size_t)HH*HH;
    const float* Uz1 = Ut + (size_t)cu1*HH;
    const float* Ur1 = Uz1 + (size_t)HH*HH;
    const float* Uh1 = Ur1 + (size_t)HH*HH;
    float bz0 = b1[cu0], br0 = b1[cu0+HH], bh0 = b1[cu0+2*HH];
    float bz1 = b1[cu1], br1 = b1[cu1+HH], bh1 = b1[cu1+2*HH];
    for (int t=0; t<TT; ++t){
        const float* mx = MXT + (size_t)t*H3*64;
        float xz0 = mx[(size_t)cu0*64 + lane];
        float xr0 = mx[(size_t)(cu0+HH)*64 + lane];
        float xh0 = mx[(size_t)(cu0+2*HH)*64 + lane];
        float xz1 = mx[(size_t)cu1*64 + lane];
        float xr1 = mx[(size_t)(cu1+HH)*64 + lane];
        float xh1 = mx[(size_t)(cu1+2*HH)*64 + lane];
        float az0=0.f, ar0=0.f, ah0=0.f, az1=0.f, ar1=0.f, ah1=0.f, hp0=0.f, hp1=0.f;
        if (t > 0){
            const unsigned long long* g8 = (const unsigned long long*)(g_h + (size_t)(t&1)*65536);
            unsigned long long sv[16];
            #pragma unroll
            for (int s=0;s<16;s++) sv[s] = aload8(g8 + s*512 + tid);
            #pragma unroll
            for (int s=0;s<16;s++) ((unsigned long long*)hs[0])[s*512 + tid] = sv[s];
            __syncthreads();
            for (int q=0;q<4;++q){
                if (q<3){
                    #pragma unroll
                    for (int s=0;s<16;s++) sv[s] = aload8(g8 + (q+1)*8192 + s*512 + tid);
                }
                const float* hb = hs[q&1];
                const float* Uz0q = Uz0 + q*256; const float* Ur0q = Ur0 + q*256; const float* Uh0q = Uh0 + q*256;
                const float* Uz1q = Uz1 + q*256; const float* Ur1q = Ur1 + q*256; const float* Uh1q = Uh1 + q*256;
                #pragma unroll 4
                for (int k4=0;k4<64;++k4){
                    float4 uz0 = *(const float4*)(Uz0q + k4*4);
                    float4 ur0 = *(const float4*)(Ur0q + k4*4);
                    float4 uh0 = *(const float4*)(Uh0q + k4*4);
                    float4 uz1 = *(const float4*)(Uz1q + k4*4);
                    float4 ur1 = *(const float4*)(Ur1q + k4*4);
                    float4 uh1 = *(const float4*)(Uh1q + k4*4);
                    float h0 = hb[(k4*4+0)*64 + lane];
                    float h1 = hb[(k4*4+1)*64 + lane];
                    float h2 = hb[(k4*4+2)*64 + lane];
                    float h3 = hb[(k4*4+3)*64 + lane];
                    az0=fmaf(h0,uz0.x,az0); ar0=fmaf(h0,ur0.x,ar0); ah0=fmaf(h0,uh0.x,ah0);
                    az1=fmaf(h0,uz1.x,az1); ar1=fmaf(h0,ur1.x,ar1); ah1=fmaf(h0,uh1.x,ah1);
                    az0=fmaf(h1,uz0.y,az0); ar0=fmaf(h1,ur0.y,ar0); ah0=fmaf(h1,uh0.y,ah0);
                    az1=fmaf(h1,uz1.y,az1); ar1=fmaf(h1,ur1.y,ar1); ah1=fmaf(h1,uh1.y,ah1);
                    az0=fmaf(h2,uz0.z,az0); ar0=fmaf(h2,ur0.z,ar0); ah0=fmaf(h2,uh0.z,ah0);
                    az1=fmaf(h2,uz1.z,az1); ar1=fmaf(h2,ur1.z,ar1); ah1=fmaf(h2,uh1.z,ah1);
                    az0=fmaf(h3,uz0.w,az0); ar0=fmaf(h3,ur0.w,ar0); ah0=fmaf(h3,uh0.w,ah0);
                    az1=fmaf(h3,uz1.w,az1); ar1=fmaf(h3,ur1.w,ar1); ah1=fmaf(h3,uh1.w,ah1);
                }
                if ((cu0>>8) == q){ hp0 = hb[(cu0&255)*64 + lane]; hp1 = hb[(cu1&255)*64 + lane]; }
                if (q<3){
                    #pragma unroll
                    for (int s=0;s<16;s++) ((unsigned long long*)hs[(q+1)&1])[s*512 + tid] = sv[s];
                }
                __syncthreads();
            }
        }
        float z0  = fsig_(xz0 + az0 + bz0);
        float r0  = fsig_(xr0 + ar0 + br0);
        float hh0 = ftanh_(xh0 + r0*(ah0 + bh0));
        float h0n = z0*hp0 + (1.f - z0)*hh0;
        float z1  = fsig_(xz1 + az1 + bz1);
        float r1  = fsig_(xr1 + ar1 + br1);
        float hh1 = ftanh_(xh1 + r1*(ah1 + bh1));
        float h1n = z1*hp1 + (1.f - z1)*hh1;
        int slot = (t+1)&1;
        __hip_atomic_store(g_h + (size_t)slot*65536 + cu0*64 + lane, h0n, __ATOMIC_RELAXED, AGENT);
        __hip_atomic_store(g_h + (size_t)slot*65536 + cu1*64 + lane, h1n, __ATOMIC_RELAXED, AGENT);
        hpe[((size_t)lane*TT + t)*HH + cu0] = h0n;
        hpe[((size_t)lane*TT + t)*HH + cu1] = h1n;
        gridbar(bar + (size_t)t*256, sub, 64);
    }
}

// ---------------- persistent decoder: 128 WGs x 512 thr ----------------
// wg 0-63: GRU matmul (8 waves x 2 units, lane = batch)
// wg 64-127: attention team for b = wg-64 (waves 0-3; waves 4-7 idle-sync)
__global__ __launch_bounds__(512) void k_dec(const float* __restrict__ hpe,
                                             const float* __restrict__ Ut,
                                             const float* __restrict__ b1,
                                             const float* __restrict__ Edec,
                                             const float* __restrict__ scale,
                                             const float* __restrict__ fcW,
                                             const float* __restrict__ fcb,
                                             float* __restrict__ g_hT,   // [2][1024][64]
                                             float* __restrict__ g_hl,   // [2][64][1024]
                                             float* __restrict__ out,
                                             int* __restrict__ idx_t,
                                             int* __restrict__ bar,
                                             int* __restrict__ flagidx){
    __shared__ float hs[2][16384];
    __shared__ float ctxs[4][1024];
    __shared__ float m_s[4], S_s[4];
    __shared__ int c_a, c_fc, go;
    int tid = threadIdx.x, wg = blockIdx.x, sub = wg & 15;
    if (tid == 0){ c_a=0; c_fc=0; go=0; }
    __syncthreads();

    if (wg < 64){
        // ============ matmul role: all 8 waves, 2 units each ============
        int lane = tid & 63;
        int cu0 = __builtin_amdgcn_readfirstlane(wg*16 + (tid>>6)*2);
        int cu1 = cu0 + 1;
        const float* Uz0 = Ut + (size_t)cu0*HH;
        const float* Ur0 = Uz0 + (size_t)HH*HH;
        const float* Uh0 = Ur0 + (size_t)HH*HH;
        const float* Uz1 = Ut + (size_t)cu1*HH;
        const float* Ur1 = Uz1 + (size_t)HH*HH;
        const float* Uh1 = Ur1 + (size_t)HH*HH;
        float bz0 = b1[cu0], br0 = b1[cu0+HH], bh0 = b1[cu0+2*HH];
        float bz1 = b1[cu1], br1 = b1[cu1+HH], bh1 = b1[cu1+2*HH];
        for (int i=0; i<TT; ++i){
            float az0=0.f, ar0=0.f, ah0=0.f, az1=0.f, ar1=0.f, ah1=0.f, hp0=0.f, hp1=0.f;
            if (i > 0){
                const unsigned long long* g8 = (const unsigned long long*)(g_hT + (size_t)(i&1)*65536);
                unsigned long long sv[16];
                #pragma unroll
                for (int s=0;s<16;s++) sv[s] = aload8(g8 + s*512 + tid);
                #pragma unroll
                for (int s=0;s<16;s++) ((unsigned long long*)hs[0])[s*512 + tid] = sv[s];
                __syncthreads();
                for (int q=0;q<4;++q){
                    if (q<3){
                        #pragma unroll
                        for (int s=0;s<16;s++) sv[s] = aload8(g8 + (q+1)*8192 + s*512 + tid);
                    }
                    const float* hb = hs[q&1];
                    const float* Uz0q = Uz0 + q*256; const float* Ur0q = Ur0 + q*256; const float* Uh0q = Uh0 + q*256;
                    const float* Uz1q = Uz1 + q*256; const float* Ur1q = Ur1 + q*256; const float* Uh1q = Uh1 + q*256;
                    #pragma unroll 4
                    for (int k4=0;k4<64;++k4){
                        float4 uz0 = *(const float4*)(Uz0q + k4*4);
                        float4 ur0 = *(const float4*)(Ur0q + k4*4);
                        float4 uh0 = *(const float4*)(Uh0q + k4*4);
                        float4 uz1 = *(const float4*)(Uz1q + k4*4);
                        float4 ur1 = *(const float4*)(Ur1q + k4*4);
                        float4 uh1 = *(const float4*)(Uh1q + k4*4);
                        float h0 = hb[(k4*4+0)*64 + lane];
                        float h1 = hb[(k4*4+1)*64 + lane];
                        float h2 = hb[(k4*4+2)*64 + lane];
                        float h3 = hb[(k4*4+3)*64 + lane];
                        az0=fmaf(h0,uz0.x,az0); ar0=fmaf(h0,ur0.x,ar0); ah0=fmaf(h0,uh0.x,ah0);
                        az1=fmaf(h0,uz1.x,az1); ar1=fmaf(h0,ur1.x,ar1); ah1=fmaf(h0,uh1.x,ah1);
                        az0=fmaf(h1,uz0.y,az0); ar0=fmaf(h1,ur0.y,ar0); ah0=fmaf(h1,uh0.y,ah0);
                        az1=fmaf(h1,uz1.y,az1); ar1=fmaf(h1,ur1.y,ar1); ah1=fmaf(h1,uh1.y,ah1);
                        az0=fmaf(h2,uz0.z,az0); ar0=fmaf(h2,ur0.z,ar0); ah0=fmaf(h2,uh0.z,ah0);
                        az1=fmaf(h2,uz1.z,az1); ar1=fmaf(h2,ur1.z,ar1); ah1=fmaf(h2,uh1.z,ah1);
                        az0=fmaf(h3,uz0.w,az0); ar0=fmaf(h3,ur0.w,ar0); ah0=fmaf(h3,uh0.w,ah0);
                        az1=fmaf(h3,uz1.w,az1); ar1=fmaf(h3,ur1.w,ar1); ah1=fmaf(h3,uh1.w,ah1);
                    }
                    if ((cu0>>8) == q){ hp0 = hb[(cu0&255)*64 + lane]; hp1 = hb[(cu1&255)*64 + lane]; }
                    if (q<3){
                        #pragma unroll
                        for (int s=0;s<16;s++) ((unsigned long long*)hs[(q+1)&1])[s*512 + tid] = sv[s];
                    }
                    __syncthreads();
                }
            }
            // wait for idx(i): single poller + LDS broadcast
            if (tid == 0){
                unsigned gy = 0; int s;
                do {
                    s = 0;
                    #pragma unroll
                    for (int c=0;c<8;c++) s += __hip_atomic_load(flagidx + (size_t)i*128 + c*16, __ATOMIC_RELAXED, AGENT);
                    if (s < 64){ if (++gy > FL_CAP) break; __builtin_amdgcn_s_sleep(1); }
                } while (s < 64);
                __hip_atomic_store(&go, i+1, __ATOMIC_RELAXED, WGRP);
            }
            { unsigned gy=0; while (__hip_atomic_load(&go, __ATOMIC_RELAXED, WGRP) < i+1){ if (++gy > LDS_CAP) break; } }
            asm volatile("" ::: "memory");
            unsigned mi = aload4(idx_t + (size_t)i*64 + lane);
            if (mi > 27u) mi = 0;
            const float* ed = Edec + (size_t)mi*H3;
            float xz0 = ed[cu0], xr0 = ed[cu0+HH], xh0 = ed[cu0+2*HH];
            float xz1 = ed[cu1], xr1 = ed[cu1+HH], xh1 = ed[cu1+2*HH];
            float z0  = fsig_(xz0 + az0 + bz0);
            float r0  = fsig_(xr0 + ar0 + br0);
            float hh0 = ftanh_(xh0 + r0*(ah0 + bh0));
            float h0n = z0*hp0 + (1.f - z0)*hh0;
            float z1  = fsig_(xz1 + az1 + bz1);
            float r1  = fsig_(xr1 + ar1 + br1);
            float hh1 = ftanh_(xh1 + r1*(ah1 + bh1));
            float h1n = z1*hp1 + (1.f - z1)*hh1;
            int slot = (i&1)^1;
            __hip_atomic_store(g_hT + (size_t)slot*65536 + cu0*64 + lane, h0n, __ATOMIC_RELAXED, AGENT);
            __hip_atomic_store(g_hT + (size_t)slot*65536 + cu1*64 + lane, h1n, __ATOMIC_RELAXED, AGENT);
            __hip_atomic_store(g_hl + (size_t)slot*65536 + (size_t)lane*HH + cu0, h0n, __ATOMIC_RELAXED, AGENT);
            __hip_atomic_store(g_hl + (size_t)slot*65536 + (size_t)lane*HH + cu1, h1n, __ATOMIC_RELAXED, AGENT);
            gridbar(bar + (size_t)i*256, sub, 128);
        }
    } else {
        int b = wg - 64;
        if (tid < 256){
            // ============ attention team, waves 0-3 ============
            int w = tid >> 6, lane = tid & 63;
            float sc[16];
            #pragma unroll
            for (int s4=0;s4<4;s4++){
                float4 v = *(const float4*)(scale + lane*16 + s4*4);
                sc[s4*4+0]=v.x; sc[s4*4+1]=v.y; sc[s4*4+2]=v.z; sc[s4*4+3]=v.w;
            }
            int j0 = w*25;
            for (int i=0; i<TT; ++i){
                float q[16];
                if (i == 0){
                    #pragma unroll
                    for (int d=0;d<16;d++) q[d]=0.f;
                } else {
                    const unsigned long long* hq8 = (const unsigned long long*)(g_hl + (size_t)(i&1)*65536 + (size_t)b*HH) + lane*8;
                    #pragma unroll
                    for (int s8=0;s8<8;s8++){
                        unsigned long long v = aload8(hq8 + s8);
                        q[2*s8+0] = __uint_as_float((unsigned)v);
                        q[2*s8+1] = __uint_as_float((unsigned)(v>>32));
                    }
                }
                if (w == 0){
                    if (i > 0){
                        float acc[NOUT];
                        #pragma unroll
                        for (int o=0;o<NOUT;o++) acc[o]=0.f;
                        float cv[16];
                        #pragma unroll
                        for (int s4=0;s4<4;s4++){
                            float4 c0 = ((const float4*)ctxs[0])[lane*4+s4];
                            float4 c1 = ((const float4*)ctxs[1])[lane*4+s4];
                            float4 c2 = ((const float4*)ctxs[2])[lane*4+s4];
                            float4 c3 = ((const float4*)ctxs[3])[lane*4+s4];
                            cv[s4*4+0]=c0.x+c1.x+c2.x+c3.x;
                            cv[s4*4+1]=c0.y+c1.y+c2.y+c3.y;
                            cv[s4*4+2]=c0.z+c1.z+c2.z+c3.z;
                            cv[s4*4+3]=c0.w+c1.w+c2.w+c3.w;
                        }
                        #pragma unroll
                        for (int dd=0;dd<16;++dd){
                            int d = lane*16 + dd;
                            const float* w0p = fcW + (size_t)d*NOUT;
                            const float* w1p = fcW + (size_t)(d+HH)*NOUT;
                            float hv=q[dd], cvv=cv[dd];
                            #pragma unroll
                            for (int o=0;o<NOUT;o++) acc[o] = fmaf(hv, w0p[o], fmaf(cvv, w1p[o], acc[o]));
                        }
                        #pragma unroll
                        for (int o=0;o<NOUT;o++){
                            #pragma unroll
                            for (int m=1;m<64;m<<=1) acc[o] += __shfl_xor(acc[o], m);
                        }
                        float bv=-3.0e38f; int bi=0;
                        #pragma unroll
                        for (int o=0;o<NOUT;o++){
                            float p = acc[o] + fcb[o];
                            acc[o] = p;
                            if (p > bv){ bv = p; bi = o; }
                        }
                        float vout = 0.f;
                        #pragma unroll
                        for (int o=0;o<NOUT;o++) if (lane == o) vout = acc[o];
                        if (lane < NOUT) out[((size_t)b*TT + (i-1))*NOUT + lane] = vout;
                        if (lane == 0){
                            __hip_atomic_store(idx_t + (size_t)i*64 + b, bi, __ATOMIC_RELAXED, AGENT);
                            wait_vm();
                        }
                    }
                    if (lane == 0){
                        __hip_atomic_fetch_add(flagidx + (size_t)i*128 + (b&7)*16, 1, __ATOMIC_RELAXED, AGENT);
                        __hip_atomic_fetch_add(&c_fc, 1, __ATOMIC_RELAXED, WGRP);
                    }
                }
                // online-softmax single pass over this wave's 25 keys
                float m = -3.0e38f, S = 0.f;
                float a[16];
                #pragma unroll
                for (int d=0;d<16;d++) a[d]=0.f;
                for (int jj=0;jj<25;jj++){
                    int j = j0 + jj;
                    const float* hpj = hpe + ((size_t)b*TT + j)*HH + lane*16;
                    float va[16];
                    {
                        float4 v0 = *(const float4*)(hpj);
                        float4 v1 = *(const float4*)(hpj+4);
                        float4 v2 = *(const float4*)(hpj+8);
                        float4 v3 = *(const float4*)(hpj+12);
                        va[0]=v0.x;va[1]=v0.y;va[2]=v0.z;va[3]=v0.w;
                        va[4]=v1.x;va[5]=v1.y;va[6]=v1.z;va[7]=v1.w;
                        va[8]=v2.x;va[9]=v2.y;va[10]=v2.z;va[11]=v2.w;
                        va[12]=v3.x;va[13]=v3.y;va[14]=v3.z;va[15]=v3.w;
                    }
                    float s = 0.f;
                    #pragma unroll
                    for (int d=0;d<16;d++) s += sc[d]*ftanh_(q[d] + va[d]);
                    #pragma unroll
                    for (int mm=1;mm<64;mm<<=1) s += __shfl_xor(s, mm);
                    float mn = fmaxf(m, s);
                    float fold = __expf(m - mn);
                    float e = __expf(s - mn);
                    S = S*fold + e;
                    #pragma unroll
                    for (int d=0;d<16;d++) a[d] = a[d]*fold + e*va[d];
                    m = mn;
                }
                if (lane == 0){ m_s[w] = m; S_s[w] = S; }
                asm volatile("s_waitcnt lgkmcnt(0)" ::: "memory");
                if (lane == 0) __hip_atomic_fetch_add(&c_a, 1, __ATOMIC_RELAXED, WGRP);
                { unsigned gy=0; while (__hip_atomic_load(&c_a, __ATOMIC_RELAXED, WGRP) < 4*(i+1)){ if (++gy > LDS_CAP) break; } }
                asm volatile("" ::: "memory");
                float M = fmaxf(fmaxf(m_s[0],m_s[1]), fmaxf(m_s[2],m_s[3]));
                float St = S_s[0]*__expf(m_s[0]-M) + S_s[1]*__expf(m_s[1]-M)
                         + S_s[2]*__expf(m_s[2]-M) + S_s[3]*__expf(m_s[3]-M);
                float g = __expf(m - M) * frcp_(St);
                // wait until fc consumed ctxs of step i-1
                { unsigned gy=0; while (__hip_atomic_load(&c_fc, __ATOMIC_RELAXED, WGRP) < i+1){ if (++gy > LDS_CAP) break; } }
                asm volatile("" ::: "memory");
                #pragma unroll
                for (int s4=0;s4<4;s4++){
                    float4 o4;
                    o4.x=a[s4*4+0]*g; o4.y=a[s4*4+1]*g;
                    o4.z=a[s4*4+2]*g; o4.w=a[s4*4+3]*g;
                    ((float4*)ctxs[w])[lane*4 + s4] = o4;
                }
                gridbar(bar + (size_t)i*256, sub, 128);
            }
            // epilogue: p(99) = [hd(100), ctx(99)] @ fc ; hd(100) in g_hl slot 0
            if (w == 0){
                const unsigned long long* hq8 = (const unsigned long long*)(g_hl + (size_t)b*HH) + lane*8;
                float q[16];
                #pragma unroll
                for (int s8=0;s8<8;s8++){
                    unsigned long long v = aload8(hq8 + s8);
                    q[2*s8+0] = __uint_as_float((unsigned)v);
                    q[2*s8+1] = __uint_as_float((unsigned)(v>>32));
                }
                float acc[NOUT];
                #pragma unroll
                for (int o=0;o<NOUT;o++) acc[o]=0.f;
                float cv[16];
                #pragma unroll
                for (int s4=0;s4<4;s4++){
                    float4 c0 = ((const float4*)ctxs[0])[lane*4+s4];
                    float4 c1 = ((const float4*)ctxs[1])[lane*4+s4];
                    float4 c2 = ((const float4*)ctxs[2])[lane*4+s4];
                    float4 c3 = ((const float4*)ctxs[3])[lane*4+s4];
                    cv[s4*4+0]=c0.x+c1.x+c2.x+c3.x;
                    cv[s4*4+1]=c0.y+c1.y+c2.y+c3.y;
                    cv[s4*4+2]=c0.z+c1.z+c2.z+c3.z;
                    cv[s4*4+3]=c0.w+c1.w+c2.w+c3.w;
                }
                #pragma unroll
                for (int dd=0;dd<16;++dd){
                    int d = lane*16 + dd;
                    const float* w0p = fcW + (size_t)d*NOUT;
                    const float* w1p = fcW + (size_t)(d+HH)*NOUT;
                    float hv=q[dd], cvv=cv[dd];
                    #pragma unroll
                    for (int o=0;o<NOUT;o++) acc[o] = fmaf(hv, w0p[o], fmaf(cvv, w1p[o], acc[o]));
                }
                #pragma unroll
                for (int o=0;o<NOUT;o++){
                    #pragma unroll
                    for (int m=1;m<64;m<<=1) acc[o] += __shfl_xor(acc[o], m);
                }
                float vout = 0.f;
                #pragma unroll
                for (int o=0;o<NOUT;o++) if (lane == o) vout = acc[o] + fcb[o];
                if (lane < NOUT) out[((size_t)b*TT + 99)*NOUT + lane] = vout;
            }
        } else {
            // waves 4-7 of attention WGs: barrier participation only
            for (int i=0;i<TT;++i) gridbar(bar + (size_t)i*256, sub, 128);
        }
    }
}

extern "C" void kernel_launch(void* const* d_in, const int* in_sizes, int n_in,
                              void* d_out, int out_size, void* d_ws, size_t ws_size,
                              hipStream_t stream){
    (void)in_sizes; (void)n_in; (void)out_size; (void)ws_size;
    const float* x     = (const float*)d_in[0];
    const float* encW  = (const float*)d_in[1];
    const float* encU  = (const float*)d_in[2];
    const float* encb  = (const float*)d_in[3];
    const float* scale = (const float*)d_in[4];
    const float* emb   = (const float*)d_in[5];
    const float* decW  = (const float*)d_in[6];
    const float* decU  = (const float*)d_in[7];
    const float* decb  = (const float*)d_in[8];
    const float* fcW   = (const float*)d_in[9];
    const float* fcb   = (const float*)d_in[10];
    float* out = (float*)d_out;
    float* ws  = (float*)d_ws;

    // ~131.2 MB total (< round-2/4/8-proven ~133 MB)
    float* MXT   = ws;                        // 19,660,800 (encoder phase only)
    float* g_hdT = MXT;                       // dec overlay: 131,072
    float* g_hdl = MXT + 131072;              // dec overlay: 131,072
    float* encUt = MXT   + 19660800;          // 3,145,728
    float* decUt = encUt + 3145728;           // 3,145,728
    float* hpe   = decUt + 3145728;           // 6,553,600
    float* Edec  = hpe   + 6553600;           // 86,016
    float* g_hT  = Edec  + 86016;             // 131,072 (enc ping-pong)
    int*   ib    = (int*)(g_hT + 131072);
    int*   bar_enc = ib;                      // 100*256 = 25,600
    int*   bar_dec = ib + 25600;              // 25,600
    int*   flagidx = ib + 51200;              // 100*128 = 12,800
    int*   idx_t   = ib + 64000;              // 100*64  = 6,400   -> 70,400 ints

    const float* encb1 = encb + H3;
    const float* decb1 = decb + H3;

    k_init<<<276,256,0,stream>>>(ib, 70400);
    k_transpose<<<dim3(96,32,2),256,0,stream>>>(encU, decU, encUt, decUt);
    k_edec<<<336,256,0,stream>>>(emb, decW, decb, Edec);
    k_mxgemm<<<dim3(48,100),256,0,stream>>>(x, encW, encb, MXT);
    k_enc<<<64,512,0,stream>>>(MXT, encUt, encb1, hpe, g_hT, bar_enc);
    k_dec<<<128,512,0,stream>>>(hpe, decUt, decb1, Edec, scale, fcW, fcb,
                                g_hdT, g_hdl, out, idx_t, bar_dec, flagidx);
}

// Round 10
// 10224.073 us; speedup vs baseline: 1.7606x; 1.7606x over previous
//
#include <hip/hip_runtime.h>

#define TT 100
#define HH 1024
#define H3 3072
#define NOUT 28

#define AGENT __HIP_MEMORY_SCOPE_AGENT
#define WGRP  __HIP_MEMORY_SCOPE_WORKGROUP
#define SPIN_CAP (1u<<20)

__device__ __forceinline__ float frcp_(float x){ return __builtin_amdgcn_rcpf(x); }
__device__ __forceinline__ float fsig_(float x){ return frcp_(1.0f + __expf(-x)); }
__device__ __forceinline__ float ftanh_(float x){ return 1.0f - 2.0f*frcp_(__expf(2.0f*x) + 1.0f); }
__device__ __forceinline__ void wait_vm(){ asm volatile("s_waitcnt vmcnt(0)" ::: "memory"); }

// device-coherent 16B load: bypass L1+L2, read at the coherence point (same
// visibility as relaxed agent-scope atomic load, but coalesces as a vector load)
__device__ __forceinline__ float4 ld_dev16(const float* p){
    float4 v;
    asm volatile("global_load_dwordx4 %0, %1, off sc0 sc1" : "=v"(v) : "v"(p) : "memory");
    return v;
}
__device__ __forceinline__ unsigned aload4(const int* p){
    return (unsigned)__hip_atomic_load(p, __ATOMIC_RELAXED, AGENT);
}

// grid barrier: 16 padded sub-counters per slot (slot stride = 256 ints), relaxed only.
// Data visibility: agent-scope atomic stores to fresh per-slot buffers (round-4/8-proven).
__device__ __forceinline__ void gridbar(int* slot, int sub, int target){
    __syncthreads();   // drains vmcnt -> stores complete before arrival
    if (threadIdx.x == 0){
        __hip_atomic_fetch_add(slot + sub*16, 1, __ATOMIC_RELAXED, AGENT);
        unsigned gy = 0; int s;
        do {
            s = 0;
            #pragma unroll
            for (int c=0;c<16;c++) s += __hip_atomic_load(slot + c*16, __ATOMIC_RELAXED, AGENT);
            if (s < target){ if (++gy > SPIN_CAP) break; __builtin_amdgcn_s_sleep(1); }
        } while (s < target);
    }
    __syncthreads();
}

// barrier among the 4 matmul waves only (LDS counter, monotonic target), capped
__device__ __forceinline__ void wbar4(int* c, int tgt){
    asm volatile("s_waitcnt lgkmcnt(0)" ::: "memory");
    if ((threadIdx.x & 63) == 0) __hip_atomic_fetch_add(c, 1, __ATOMIC_RELAXED, WGRP);
    unsigned gy = 0;
    while (__hip_atomic_load(c, __ATOMIC_RELAXED, WGRP) < tgt){ if (++gy > SPIN_CAP) break; }
    asm volatile("" ::: "memory");
}

// ---------------- init: zero control ints ----------------
__global__ void k_init(int* ib, int n){
    int g = blockIdx.x*256 + threadIdx.x;
    if (g < n) ib[g] = 0;
}

// ---------------- transpose U [1024][3072] -> Ut [3072][1024] ----------------
__global__ __launch_bounds__(256) void k_transpose(const float* __restrict__ U0,
                                                   const float* __restrict__ U1,
                                                   float* __restrict__ T0,
                                                   float* __restrict__ T1){
    const float* U = blockIdx.z ? U1 : U0;
    float*       T = blockIdx.z ? T1 : T0;
    __shared__ float tile[32][33];
    int tx = threadIdx.x & 31, ty = threadIdx.x >> 5;
    int j0 = blockIdx.x*32, k0 = blockIdx.y*32;
    #pragma unroll
    for (int q=0;q<4;q++){
        int kr = ty + q*8;
        tile[kr][tx] = U[(size_t)(k0+kr)*H3 + j0 + tx];
    }
    __syncthreads();
    #pragma unroll
    for (int q=0;q<4;q++){
        int jr = ty + q*8;
        T[(size_t)(j0+jr)*HH + k0 + tx] = tile[tx][jr];
    }
}

// ---------------- Edec[28][3072] = emb @ decW + decb[0] ----------------
__global__ __launch_bounds__(256) void k_edec(const float* __restrict__ emb,
                                              const float* __restrict__ W,
                                              const float* __restrict__ b0,
                                              float* __restrict__ E){
    int gid = blockIdx.x*256 + threadIdx.x;   // 28*3072 = 86016
    int v = gid / H3, j = gid - v*H3;
    float acc = b0[j];
    const float* er = emb + (size_t)v*HH;
    #pragma unroll 4
    for (int k=0;k<HH;k++) acc = fmaf(er[k], W[(size_t)k*H3 + j], acc);
    E[gid] = acc;
}

// ---------------- MXT[t][col][b] = (x2d @ encW + encb[0]) transposed ----------------
__global__ __launch_bounds__(256) void k_mxgemm(const float* __restrict__ A,
                                                const float* __restrict__ W,
                                                const float* __restrict__ b0,
                                                float* __restrict__ MXT){
    __shared__ float aT[32*68];
    __shared__ float bL[32*68];
    int tid = threadIdx.x;
    int row0 = blockIdx.y*64, col0 = blockIdx.x*64;
    int arow = tid>>2, acs = (tid&3)*4;
    int bk   = tid>>3, bcs = (tid&7)*4;
    int ty = tid>>4, tx = tid&15;
    float acc[4][4] = {};
    for (int kk=0; kk<HH; kk+=32){
        #pragma unroll
        for (int i=0;i<2;i++){
            int c = acs + i*16;
            float4 v = *(const float4*)(A + (size_t)(row0+arow)*HH + kk + c);
            aT[(c+0)*68 + arow] = v.x; aT[(c+1)*68 + arow] = v.y;
            aT[(c+2)*68 + arow] = v.z; aT[(c+3)*68 + arow] = v.w;
        }
        #pragma unroll
        for (int i=0;i<2;i++){
            int c = bcs + i*32;
            float4 v = *(const float4*)(W + (size_t)(kk+bk)*H3 + col0 + c);
            *(float4*)(bL + bk*68 + c) = v;
        }
        __syncthreads();
        #pragma unroll
        for (int k=0;k<32;k++){
            float4 a4 = *(const float4*)(aT + k*68 + ty*4);
            float4 b4 = *(const float4*)(bL + k*68 + tx*4);
            acc[0][0]=fmaf(a4.x,b4.x,acc[0][0]); acc[0][1]=fmaf(a4.x,b4.y,acc[0][1]);
            acc[0][2]=fmaf(a4.x,b4.z,acc[0][2]); acc[0][3]=fmaf(a4.x,b4.w,acc[0][3]);
            acc[1][0]=fmaf(a4.y,b4.x,acc[1][0]); acc[1][1]=fmaf(a4.y,b4.y,acc[1][1]);
            acc[1][2]=fmaf(a4.y,b4.z,acc[1][2]); acc[1][3]=fmaf(a4.y,b4.w,acc[1][3]);
            acc[2][0]=fmaf(a4.z,b4.x,acc[2][0]); acc[2][1]=fmaf(a4.z,b4.y,acc[2][1]);
            acc[2][2]=fmaf(a4.z,b4.z,acc[2][2]); acc[2][3]=fmaf(a4.z,b4.w,acc[2][3]);
            acc[3][0]=fmaf(a4.w,b4.x,acc[3][0]); acc[3][1]=fmaf(a4.w,b4.y,acc[3][1]);
            acc[3][2]=fmaf(a4.w,b4.z,acc[3][2]); acc[3][3]=fmaf(a4.w,b4.w,acc[3][3]);
        }
        __syncthreads();
    }
    float4 bb = *(const float4*)(b0 + col0 + tx*4);
    #pragma unroll
    for (int i=0;i<4;i++){
        int r = row0 + ty*4 + i;
        int bq = r / 100; int tq = r - bq*100;
        float v0 = acc[i][0] + bb.x, v1 = acc[i][1] + bb.y;
        float v2 = acc[i][2] + bb.z, v3 = acc[i][3] + bb.w;
        float* dst = MXT + ((size_t)tq*H3 + col0 + tx*4)*64 + bq;
        dst[0]   = v0; dst[64]  = v1; dst[128] = v2; dst[192] = v3;
    }
}

// ---------------- persistent encoder: 256 WGs x 256 thr ----------------
// hT = ping-pong [2][1024][64]; staged to LDS via coalesced device-coherent 16B loads
__global__ __launch_bounds__(256) void k_enc(const float* __restrict__ MXT,
                                             const float* __restrict__ Ut,
                                             const float* __restrict__ b1,
                                             float* __restrict__ hpe,
                                             float* __restrict__ hT,
                                             int* __restrict__ bar){
    __shared__ float hs[2][16384];
    int tid = threadIdx.x, lane = tid & 63;
    int wg = blockIdx.x;
    int sub = wg & 15;
    int cu = __builtin_amdgcn_readfirstlane(wg*4 + (tid>>6));
    const float* Uz = Ut + (size_t)cu*HH;
    const float* Ur = Uz + (size_t)HH*HH;
    const float* Uh = Ur + (size_t)HH*HH;
    float bz = b1[cu], br = b1[cu+HH], bh = b1[cu+2*HH];
    for (int t=0; t<TT; ++t){
        int cur = t & 1;
        const float* mx = MXT + (size_t)t*H3*64;
        float xz = mx[(size_t)cu*64 + lane];
        float xr = mx[(size_t)(cu+HH)*64 + lane];
        float xh = mx[(size_t)(cu+2*HH)*64 + lane];
        float az=0.f, ar=0.f, ah=0.f, hp=0.f;
        if (t > 0){
            const float* gq = hT + (size_t)cur*65536;
            float4 sv[16];
            #pragma unroll
            for (int s=0;s<16;s++) sv[s] = ld_dev16(gq + 4*(size_t)(s*256 + tid));
            wait_vm();
            #pragma unroll
            for (int s=0;s<16;s++) ((float4*)hs[0])[s*256 + tid] = sv[s];
            __syncthreads();
            for (int q=0;q<4;++q){
                if (q<3){
                    #pragma unroll
                    for (int s=0;s<16;s++) sv[s] = ld_dev16(gq + (size_t)(q+1)*16384 + 4*(size_t)(s*256 + tid));
                }
                const float* hb = hs[q&1];
                const float* Uzq = Uz + q*256;
                const float* Urq = Ur + q*256;
                const float* Uhq = Uh + q*256;
                #pragma unroll 8
                for (int k=0;k<256;++k){
                    float h = hb[k*64 + lane];
                    az = fmaf(h, Uzq[k], az);
                    ar = fmaf(h, Urq[k], ar);
                    ah = fmaf(h, Uhq[k], ah);
                }
                if ((cu>>8) == q) hp = hb[(cu&255)*64 + lane];
                if (q<3){
                    wait_vm();
                    #pragma unroll
                    for (int s=0;s<16;s++) ((float4*)hs[(q+1)&1])[s*256 + tid] = sv[s];
                }
                __syncthreads();
            }
        }
        float z  = fsig_(xz + az + bz);
        float r  = fsig_(xr + ar + br);
        float hh = ftanh_(xh + r*(ah + bh));
        float hnew = z*hp + (1.f - z)*hh;
        __hip_atomic_store(hT + (size_t)(cur^1)*65536 + cu*64 + lane, hnew, __ATOMIC_RELAXED, AGENT);
        hpe[((size_t)lane*TT + t)*HH + cu] = hnew;
        gridbar(bar + (size_t)t*256, sub, 256);
    }
}

// ---------------- persistent decoder: 256 WGs x 512 thr ----------------
// waves 0-3: GRU matmul (unit = wg*4+wave, lane = batch); waves 4-7 on wg<64: attention team b=wg
__global__ __launch_bounds__(512) void k_dec(const float* __restrict__ hpe,
                                             const float* __restrict__ Ut,
                                             const float* __restrict__ b1,
                                             const float* __restrict__ Edec,
                                             const float* __restrict__ scale,
                                             const float* __restrict__ fcW,
                                             const float* __restrict__ fcb,
                                             float* __restrict__ hdT,
                                             float* __restrict__ hdl,
                                             float* __restrict__ out,
                                             int* __restrict__ idx_t,
                                             int* __restrict__ bar,
                                             int* __restrict__ flagidx){
    __shared__ float hs[2][16384];
    __shared__ float ctxs[4][1024];
    __shared__ float m_s[4], S_s[4];
    __shared__ int c_a, c_fc, go, cstg;
    int tid = threadIdx.x, wg = blockIdx.x;
    if (tid == 0){ c_a=0; c_fc=0; go=0; cstg=0; }
    __syncthreads();

    if (tid < 256){
        // ============ matmul role ============
        int lane = tid & 63;
        int sub = wg & 15;
        int cu = __builtin_amdgcn_readfirstlane(wg*4 + (tid>>6));
        const float* Uz = Ut + (size_t)cu*HH;
        const float* Ur = Uz + (size_t)HH*HH;
        const float* Uh = Ur + (size_t)HH*HH;
        float bz = b1[cu], br = b1[cu+HH], bh = b1[cu+2*HH];
        int stgt = 0;
        for (int i=0; i<TT; ++i){
            int cur = i & 1;
            float az=0.f, ar=0.f, ah=0.f, hp=0.f;
            if (i > 0){
                const float* gq = hdT + (size_t)cur*65536;
                float4 sv[16];
                #pragma unroll
                for (int s=0;s<16;s++) sv[s] = ld_dev16(gq + 4*(size_t)(s*256 + tid));
                wait_vm();
                #pragma unroll
                for (int s=0;s<16;s++) ((float4*)hs[0])[s*256 + tid] = sv[s];
                wbar4(&cstg, stgt += 4);
                for (int q=0;q<4;++q){
                    if (q<3){
                        #pragma unroll
                        for (int s=0;s<16;s++) sv[s] = ld_dev16(gq + (size_t)(q+1)*16384 + 4*(size_t)(s*256 + tid));
                    }
                    const float* hb = hs[q&1];
                    const float* Uzq = Uz + q*256;
                    const float* Urq = Ur + q*256;
                    const float* Uhq = Uh + q*256;
                    #pragma unroll 8
                    for (int k=0;k<256;++k){
                        float h = hb[k*64 + lane];
                        az = fmaf(h, Uzq[k], az);
                        ar = fmaf(h, Urq[k], ar);
                        ah = fmaf(h, Uhq[k], ah);
                    }
                    if ((cu>>8) == q) hp = hb[(cu&255)*64 + lane];
                    if (q<3){
                        wait_vm();
                        #pragma unroll
                        for (int s=0;s<16;s++) ((float4*)hs[(q+1)&1])[s*256 + tid] = sv[s];
                    }
                    wbar4(&cstg, stgt += 4);
                }
            }
            // wait for idx(i): single poller + LDS broadcast
            if (tid == 0){
                unsigned gy = 0; int s;
                do {
                    s = 0;
                    #pragma unroll
                    for (int c=0;c<8;c++) s += __hip_atomic_load(flagidx + (size_t)i*128 + c*16, __ATOMIC_RELAXED, AGENT);
                    if (s < 64){ if (++gy > SPIN_CAP) break; __builtin_amdgcn_s_sleep(1); }
                } while (s < 64);
                __hip_atomic_store(&go, i+1, __ATOMIC_RELAXED, WGRP);
            }
            { unsigned gy=0; while (__hip_atomic_load(&go, __ATOMIC_RELAXED, WGRP) < i+1){ if (++gy > SPIN_CAP) break; } }
            asm volatile("" ::: "memory");
            unsigned mi = aload4(idx_t + (size_t)i*64 + lane);
            if (mi > 27u) mi = 0;
            const float* ed = Edec + (size_t)mi*H3;
            float xz = ed[cu], xr = ed[cu+HH], xh = ed[cu+2*HH];
            float z  = fsig_(xz + az + bz);
            float r  = fsig_(xr + ar + br);
            float hh = ftanh_(xh + r*(ah + bh));
            float hnew = z*hp + (1.f - z)*hh;
            __hip_atomic_store(hdT + (size_t)(cur^1)*65536 + cu*64 + lane, hnew, __ATOMIC_RELAXED, AGENT);
            __hip_atomic_store(hdl + (size_t)(cur^1)*65536 + (size_t)lane*HH + cu, hnew, __ATOMIC_RELAXED, AGENT);
            gridbar(bar + (size_t)i*256, sub, 256);
        }
    } else if (wg < 64){
        // ============ attention team for batch b = wg ============
        int t2 = tid - 256;
        int w = t2 >> 6, lane = t2 & 63, b = wg;
        float sc[16];
        #pragma unroll
        for (int s4=0;s4<4;s4++){
            float4 v = *(const float4*)(scale + lane*16 + s4*4);
            sc[s4*4+0]=v.x; sc[s4*4+1]=v.y; sc[s4*4+2]=v.z; sc[s4*4+3]=v.w;
        }
        int j0 = w*25;
        for (int i=0; i<TT; ++i){
            float q[16];
            if (i == 0){
                #pragma unroll
                for (int d=0;d<16;d++) q[d]=0.f;
            } else {
                const float* hq = hdl + (size_t)(i&1)*65536 + (size_t)b*HH + lane*16;
                float4 q0 = ld_dev16(hq), q1 = ld_dev16(hq+4), q2 = ld_dev16(hq+8), q3 = ld_dev16(hq+12);
                wait_vm();
                q[0]=q0.x;q[1]=q0.y;q[2]=q0.z;q[3]=q0.w;
                q[4]=q1.x;q[5]=q1.y;q[6]=q1.z;q[7]=q1.w;
                q[8]=q2.x;q[9]=q2.y;q[10]=q2.z;q[11]=q2.w;
                q[12]=q3.x;q[13]=q3.y;q[14]=q3.z;q[15]=q3.w;
            }
            if (w == 0){
                if (i > 0){
                    float acc[NOUT];
                    #pragma unroll
                    for (int o=0;o<NOUT;o++) acc[o]=0.f;
                    float cv[16];
                    #pragma unroll
                    for (int s4=0;s4<4;s4++){
                        float4 c0 = ((const float4*)ctxs[0])[lane*4+s4];
                        float4 c1 = ((const float4*)ctxs[1])[lane*4+s4];
                        float4 c2 = ((const float4*)ctxs[2])[lane*4+s4];
                        float4 c3 = ((const float4*)ctxs[3])[lane*4+s4];
                        cv[s4*4+0]=c0.x+c1.x+c2.x+c3.x;
                        cv[s4*4+1]=c0.y+c1.y+c2.y+c3.y;
                        cv[s4*4+2]=c0.z+c1.z+c2.z+c3.z;
                        cv[s4*4+3]=c0.w+c1.w+c2.w+c3.w;
                    }
                    #pragma unroll
                    for (int dd=0;dd<16;++dd){
                        int d = lane*16 + dd;
                        const float* w0p = fcW + (size_t)d*NOUT;
                        const float* w1p = fcW + (size_t)(d+HH)*NOUT;
                        float hv=q[dd], cvv=cv[dd];
                        #pragma unroll
                        for (int o=0;o<NOUT;o++) acc[o] = fmaf(hv, w0p[o], fmaf(cvv, w1p[o], acc[o]));
                    }
                    #pragma unroll
                    for (int o=0;o<NOUT;o++){
                        #pragma unroll
                        for (int m=1;m<64;m<<=1) acc[o] += __shfl_xor(acc[o], m);
                    }
                    float bv=-3.0e38f; int bi=0;
                    #pragma unroll
                    for (int o=0;o<NOUT;o++){
                        float p = acc[o] + fcb[o];
                        acc[o] = p;
                        if (p > bv){ bv = p; bi = o; }
                    }
                    float vout = 0.f;
                    #pragma unroll
                    for (int o=0;o<NOUT;o++) if (lane == o) vout = acc[o];
                    if (lane < NOUT) out[((size_t)b*TT + (i-1))*NOUT + lane] = vout;
                    if (lane == 0){
                        __hip_atomic_store(idx_t + (size_t)i*64 + b, bi, __ATOMIC_RELAXED, AGENT);
                        asm volatile("s_waitcnt vmcnt(0)" ::: "memory");
                    }
                }
                if (lane == 0){
                    __hip_atomic_fetch_add(flagidx + (size_t)i*128 + (b&7)*16, 1, __ATOMIC_RELAXED, AGENT);
                    __hip_atomic_fetch_add(&c_fc, 1, __ATOMIC_RELAXED, WGRP);
                }
            }
            // ---- online-softmax single pass over this wave's 25 keys (hpe read ONCE) ----
            float m = -3.0e38f, S = 0.f;
            float a[16];
            #pragma unroll
            for (int d=0;d<16;d++) a[d]=0.f;
            for (int jj=0;jj<25;jj++){
                int j = j0 + jj;
                const float* hpj = hpe + ((size_t)b*TT + j)*HH + lane*16;
                float va[16];
                {
                    float4 v0 = *(const float4*)(hpj);
                    float4 v1 = *(const float4*)(hpj+4);
                    float4 v2 = *(const float4*)(hpj+8);
                    float4 v3 = *(const float4*)(hpj+12);
                    va[0]=v0.x;va[1]=v0.y;va[2]=v0.z;va[3]=v0.w;
                    va[4]=v1.x;va[5]=v1.y;va[6]=v1.z;va[7]=v1.w;
                    va[8]=v2.x;va[9]=v2.y;va[10]=v2.z;va[11]=v2.w;
                    va[12]=v3.x;va[13]=v3.y;va[14]=v3.z;va[15]=v3.w;
                }
                float s = 0.f;
                #pragma unroll
                for (int d=0;d<16;d++) s += sc[d]*ftanh_(q[d] + va[d]);
                #pragma unroll
                for (int mm=1;mm<64;mm<<=1) s += __shfl_xor(s, mm);
                float mn = fmaxf(m, s);
                float fold = __expf(m - mn);
                float e = __expf(s - mn);
                S = S*fold + e;
                #pragma unroll
                for (int d=0;d<16;d++) a[d] = a[d]*fold + e*va[d];
                m = mn;
            }
            if (lane == 0){ m_s[w] = m; S_s[w] = S; }
            asm volatile("s_waitcnt lgkmcnt(0)" ::: "memory");
            if (lane == 0) __hip_atomic_fetch_add(&c_a, 1, __ATOMIC_RELAXED, WGRP);
            { unsigned gy=0; while (__hip_atomic_load(&c_a, __ATOMIC_RELAXED, WGRP) < 4*(i+1)){ if (++gy > SPIN_CAP) break; } }
            asm volatile("" ::: "memory");
            float M = fmaxf(fmaxf(m_s[0],m_s[1]), fmaxf(m_s[2],m_s[3]));
            float St = S_s[0]*__expf(m_s[0]-M) + S_s[1]*__expf(m_s[1]-M)
                     + S_s[2]*__expf(m_s[2]-M) + S_s[3]*__expf(m_s[3]-M);
            float g = __expf(m - M) * frcp_(St);
            // wait until fc consumed ctxs of step i-1
            { unsigned gy=0; while (__hip_atomic_load(&c_fc, __ATOMIC_RELAXED, WGRP) < i+1){ if (++gy > SPIN_CAP) break; } }
            asm volatile("" ::: "memory");
            #pragma unroll
            for (int s4=0;s4<4;s4++){
                float4 o4;
                o4.x=a[s4*4+0]*g; o4.y=a[s4*4+1]*g;
                o4.z=a[s4*4+2]*g; o4.w=a[s4*4+3]*g;
                ((float4*)ctxs[w])[lane*4 + s4] = o4;
            }
            gridbar(bar + (size_t)i*256, wg & 15, 256);
        }
        // epilogue: p(99) = [hd(100), ctx(99)] @ fc ; hd(100) is in hdl slot 0
        if (w == 0){
            const float* hq = hdl + (size_t)b*HH + lane*16;
            float4 q0 = ld_dev16(hq), q1 = ld_dev16(hq+4), q2 = ld_dev16(hq+8), q3 = ld_dev16(hq+12);
            wait_vm();
            float q[16];
            q[0]=q0.x;q[1]=q0.y;q[2]=q0.z;q[3]=q0.w;
            q[4]=q1.x;q[5]=q1.y;q[6]=q1.z;q[7]=q1.w;
            q[8]=q2.x;q[9]=q2.y;q[10]=q2.z;q[11]=q2.w;
            q[12]=q3.x;q[13]=q3.y;q[14]=q3.z;q[15]=q3.w;
            float acc[NOUT];
            #pragma unroll
            for (int o=0;o<NOUT;o++) acc[o]=0.f;
            float cv[16];
            #pragma unroll
            for (int s4=0;s4<4;s4++){
                float4 c0 = ((const float4*)ctxs[0])[lane*4+s4];
                float4 c1 = ((const float4*)ctxs[1])[lane*4+s4];
                float4 c2 = ((const float4*)ctxs[2])[lane*4+s4];
                float4 c3 = ((const float4*)ctxs[3])[lane*4+s4];
                cv[s4*4+0]=c0.x+c1.x+c2.x+c3.x;
                cv[s4*4+1]=c0.y+c1.y+c2.y+c3.y;
                cv[s4*4+2]=c0.z+c1.z+c2.z+c3.z;
                cv[s4*4+3]=c0.w+c1.w+c2.w+c3.w;
            }
            #pragma unroll
            for (int dd=0;dd<16;++dd){
                int d = lane*16 + dd;
                const float* w0p = fcW + (size_t)d*NOUT;
                const float* w1p = fcW + (size_t)(d+HH)*NOUT;
                float hv=q[dd], cvv=cv[dd];
                #pragma unroll
                for (int o=0;o<NOUT;o++) acc[o] = fmaf(hv, w0p[o], fmaf(cvv, w1p[o], acc[o]));
            }
            #pragma unroll
            for (int o=0;o<NOUT;o++){
                #pragma unroll
                for (int m=1;m<64;m<<=1) acc[o] += __shfl_xor(acc[o], m);
            }
            float vout = 0.f;
            #pragma unroll
            for (int o=0;o<NOUT;o++) if (lane == o) vout = acc[o] + fcb[o];
            if (lane < NOUT) out[((size_t)b*TT + 99)*NOUT + lane] = vout;
        }
    } else {
        for (int i=0;i<TT;++i) gridbar(bar + (size_t)i*256, wg & 15, 256);
    }
}

extern "C" void kernel_launch(void* const* d_in, const int* in_sizes, int n_in,
                              void* d_out, int out_size, void* d_ws, size_t ws_size,
                              hipStream_t stream){
    (void)in_sizes; (void)n_in; (void)out_size; (void)ws_size;
    const float* x     = (const float*)d_in[0];
    const float* encW  = (const float*)d_in[1];
    const float* encU  = (const float*)d_in[2];
    const float* encb  = (const float*)d_in[3];
    const float* scale = (const float*)d_in[4];
    const float* emb   = (const float*)d_in[5];
    const float* decW  = (const float*)d_in[6];
    const float* decU  = (const float*)d_in[7];
    const float* decb  = (const float*)d_in[8];
    const float* fcW   = (const float*)d_in[9];
    const float* fcb   = (const float*)d_in[10];
    float* out = (float*)d_out;
    float* ws  = (float*)d_ws;

    // ~132.2 MB total (round-4/8-proven footprint)
    float* MXT   = ws;                        // 19,660,800 (encoder phase only)
    float* hdT   = MXT;                       // dec overlay: 2*65,536 ping-pong [k][b]
    float* hdl   = MXT + 131072;              // dec overlay: 2*65,536 ping-pong [b][k]
    float* encUt = MXT   + 19660800;          // 3,145,728
    float* decUt = encUt + 3145728;           // 3,145,728
    float* hpe   = decUt + 3145728;           // 6,553,600
    float* Edec  = hpe   + 6553600;           // 86,016
    float* hT    = Edec  + 86016;             // 2*65,536 ping-pong [k][b] (encoder)
    int*   ib    = (int*)(hT + 131072);
    int*   bar_enc = ib;                      // 100*256
    int*   bar_dec = ib + 25600;              // 100*256
    int*   flagidx = ib + 51200;              // 100*128
    int*   idx_t   = ib + 64000;              // 100*64   (total 70,400 ints)

    const float* encb1 = encb + H3;
    const float* decb1 = decb + H3;

    k_init<<<276,256,0,stream>>>(ib, 70400);
    k_transpose<<<dim3(96,32,2),256,0,stream>>>(encU, decU, encUt, decUt);
    k_edec<<<336,256,0,stream>>>(emb, decW, decb, Edec);
    k_mxgemm<<<dim3(48,100),256,0,stream>>>(x, encW, encb, MXT);
    k_enc<<<256,256,0,stream>>>(MXT, encUt, encb1, hpe, hT, bar_enc);
    k_dec<<<256,512,0,stream>>>(hpe, decUt, decb1, Edec, scale, fcW, fcb,
                                hdT, hdl, out, idx_t, bar_dec, flagidx);
}

// Round 11
// 10140.694 us; speedup vs baseline: 1.7751x; 1.0082x over previous
//
#include <hip/hip_runtime.h>

#define TT 100
#define HH 1024
#define H3 3072
#define NOUT 28

#define AGENT __HIP_MEMORY_SCOPE_AGENT
#define WGRP  __HIP_MEMORY_SCOPE_WORKGROUP
#define SPIN_CAP (1u<<20)

__device__ __forceinline__ float frcp_(float x){ return __builtin_amdgcn_rcpf(x); }
__device__ __forceinline__ float fsig_(float x){ return frcp_(1.0f + __expf(-x)); }
__device__ __forceinline__ float ftanh_(float x){ return 1.0f - 2.0f*frcp_(__expf(2.0f*x) + 1.0f); }
__device__ __forceinline__ void wait_vm(){ asm volatile("s_waitcnt vmcnt(0)" ::: "memory"); }

// device-coherent 16B load: bypass L1+L2, read at the coherence point
__device__ __forceinline__ float4 ld_dev16(const float* p){
    float4 v;
    asm volatile("global_load_dwordx4 %0, %1, off sc0 sc1" : "=v"(v) : "v"(p) : "memory");
    return v;
}
// device-coherent 4B load (coalesces across a wave)
__device__ __forceinline__ int ld_dev4i(const int* p){
    int v;
    asm volatile("global_load_dword %0, %1, off sc0 sc1" : "=v"(v) : "v"(p) : "memory");
    return v;
}
// device-coherent 4B store: write-through to coherence point, write-combining capable
__device__ __forceinline__ void st_dev4(float* p, float v){
    asm volatile("global_store_dword %0, %1, off sc0 sc1" :: "v"(p), "v"(v) : "memory");
}
__device__ __forceinline__ unsigned aload4(const int* p){
    return (unsigned)__hip_atomic_load(p, __ATOMIC_RELAXED, AGENT);
}

// grid barrier: 16 padded sub-counters per slot (slot stride = 256 ints), relaxed only.
// __syncthreads drains vmcnt -> all sc0sc1 publishes complete before arrival.
__device__ __forceinline__ void gridbar(int* slot, int sub, int target){
    __syncthreads();
    if (threadIdx.x == 0){
        __hip_atomic_fetch_add(slot + sub*16, 1, __ATOMIC_RELAXED, AGENT);
        unsigned gy = 0; int s;
        do {
            s = 0;
            #pragma unroll
            for (int c=0;c<16;c++) s += __hip_atomic_load(slot + c*16, __ATOMIC_RELAXED, AGENT);
            if (s < target){ if (++gy > SPIN_CAP) break; __builtin_amdgcn_s_sleep(4); }
        } while (s < target);
    }
    __syncthreads();
}

// barrier among the 4 matmul waves only (LDS counter, monotonic target), capped
__device__ __forceinline__ void wbar4(int* c, int tgt){
    asm volatile("s_waitcnt lgkmcnt(0)" ::: "memory");
    if ((threadIdx.x & 63) == 0) __hip_atomic_fetch_add(c, 1, __ATOMIC_RELAXED, WGRP);
    unsigned gy = 0;
    while (__hip_atomic_load(c, __ATOMIC_RELAXED, WGRP) < tgt){ if (++gy > SPIN_CAP) break; }
    asm volatile("" ::: "memory");
}

// ---------------- init: zero control ints ----------------
__global__ void k_init(int* ib, int n){
    int g = blockIdx.x*256 + threadIdx.x;
    if (g < n) ib[g] = 0;
}

// ---------------- transpose U [1024][3072] -> Ut [3072][1024] ----------------
__global__ __launch_bounds__(256) void k_transpose(const float* __restrict__ U0,
                                                   const float* __restrict__ U1,
                                                   float* __restrict__ T0,
                                                   float* __restrict__ T1){
    const float* U = blockIdx.z ? U1 : U0;
    float*       T = blockIdx.z ? T1 : T0;
    __shared__ float tile[32][33];
    int tx = threadIdx.x & 31, ty = threadIdx.x >> 5;
    int j0 = blockIdx.x*32, k0 = blockIdx.y*32;
    #pragma unroll
    for (int q=0;q<4;q++){
        int kr = ty + q*8;
        tile[kr][tx] = U[(size_t)(k0+kr)*H3 + j0 + tx];
    }
    __syncthreads();
    #pragma unroll
    for (int q=0;q<4;q++){
        int jr = ty + q*8;
        T[(size_t)(j0+jr)*HH + k0 + tx] = tile[tx][jr];
    }
}

// ---------------- Edec[28][3072] = emb @ decW + decb[0] ----------------
__global__ __launch_bounds__(256) void k_edec(const float* __restrict__ emb,
                                              const float* __restrict__ W,
                                              const float* __restrict__ b0,
                                              float* __restrict__ E){
    int gid = blockIdx.x*256 + threadIdx.x;   // 28*3072 = 86016
    int v = gid / H3, j = gid - v*H3;
    float acc = b0[j];
    const float* er = emb + (size_t)v*HH;
    #pragma unroll 4
    for (int k=0;k<HH;k++) acc = fmaf(er[k], W[(size_t)k*H3 + j], acc);
    E[gid] = acc;
}

// ---------------- MXT[t][col][b] = (x2d @ encW + encb[0]) transposed ----------------
__global__ __launch_bounds__(256) void k_mxgemm(const float* __restrict__ A,
                                                const float* __restrict__ W,
                                                const float* __restrict__ b0,
                                                float* __restrict__ MXT){
    __shared__ float aT[32*68];
    __shared__ float bL[32*68];
    int tid = threadIdx.x;
    int row0 = blockIdx.y*64, col0 = blockIdx.x*64;
    int arow = tid>>2, acs = (tid&3)*4;
    int bk   = tid>>3, bcs = (tid&7)*4;
    int ty = tid>>4, tx = tid&15;
    float acc[4][4] = {};
    for (int kk=0; kk<HH; kk+=32){
        #pragma unroll
        for (int i=0;i<2;i++){
            int c = acs + i*16;
            float4 v = *(const float4*)(A + (size_t)(row0+arow)*HH + kk + c);
            aT[(c+0)*68 + arow] = v.x; aT[(c+1)*68 + arow] = v.y;
            aT[(c+2)*68 + arow] = v.z; aT[(c+3)*68 + arow] = v.w;
        }
        #pragma unroll
        for (int i=0;i<2;i++){
            int c = bcs + i*32;
            float4 v = *(const float4*)(W + (size_t)(kk+bk)*H3 + col0 + c);
            *(float4*)(bL + bk*68 + c) = v;
        }
        __syncthreads();
        #pragma unroll
        for (int k=0;k<32;k++){
            float4 a4 = *(const float4*)(aT + k*68 + ty*4);
            float4 b4 = *(const float4*)(bL + k*68 + tx*4);
            acc[0][0]=fmaf(a4.x,b4.x,acc[0][0]); acc[0][1]=fmaf(a4.x,b4.y,acc[0][1]);
            acc[0][2]=fmaf(a4.x,b4.z,acc[0][2]); acc[0][3]=fmaf(a4.x,b4.w,acc[0][3]);
            acc[1][0]=fmaf(a4.y,b4.x,acc[1][0]); acc[1][1]=fmaf(a4.y,b4.y,acc[1][1]);
            acc[1][2]=fmaf(a4.y,b4.z,acc[1][2]); acc[1][3]=fmaf(a4.y,b4.w,acc[1][3]);
            acc[2][0]=fmaf(a4.z,b4.x,acc[2][0]); acc[2][1]=fmaf(a4.z,b4.y,acc[2][1]);
            acc[2][2]=fmaf(a4.z,b4.z,acc[2][2]); acc[2][3]=fmaf(a4.z,b4.w,acc[2][3]);
            acc[3][0]=fmaf(a4.w,b4.x,acc[3][0]); acc[3][1]=fmaf(a4.w,b4.y,acc[3][1]);
            acc[3][2]=fmaf(a4.w,b4.z,acc[3][2]); acc[3][3]=fmaf(a4.w,b4.w,acc[3][3]);
        }
        __syncthreads();
    }
    float4 bb = *(const float4*)(b0 + col0 + tx*4);
    #pragma unroll
    for (int i=0;i<4;i++){
        int r = row0 + ty*4 + i;
        int bq = r / 100; int tq = r - bq*100;
        float v0 = acc[i][0] + bb.x, v1 = acc[i][1] + bb.y;
        float v2 = acc[i][2] + bb.z, v3 = acc[i][3] + bb.w;
        float* dst = MXT + ((size_t)tq*H3 + col0 + tx*4)*64 + bq;
        dst[0]   = v0; dst[64]  = v1; dst[128] = v2; dst[192] = v3;
    }
}

// ---------------- persistent encoder: 256 WGs x 256 thr ----------------
__global__ __launch_bounds__(256) void k_enc(const float* __restrict__ MXT,
                                             const float* __restrict__ Ut,
                                             const float* __restrict__ b1,
                                             float* __restrict__ hpe,
                                             float* __restrict__ hT,
                                             int* __restrict__ bar){
    __shared__ float hs[2][16384];
    int tid = threadIdx.x, lane = tid & 63;
    int wg = blockIdx.x;
    int sub = wg & 15;
    int cu = __builtin_amdgcn_readfirstlane(wg*4 + (tid>>6));
    const float* Uz = Ut + (size_t)cu*HH;
    const float* Ur = Uz + (size_t)HH*HH;
    const float* Uh = Ur + (size_t)HH*HH;
    float bz = b1[cu], br = b1[cu+HH], bh = b1[cu+2*HH];
    for (int t=0; t<TT; ++t){
        int cur = t & 1;
        const float* mx = MXT + (size_t)t*H3*64;
        float xz = mx[(size_t)cu*64 + lane];
        float xr = mx[(size_t)(cu+HH)*64 + lane];
        float xh = mx[(size_t)(cu+2*HH)*64 + lane];
        float az=0.f, ar=0.f, ah=0.f, hp=0.f;
        if (t > 0){
            const float* gq = hT + (size_t)cur*65536;
            float4 sv[16];
            #pragma unroll
            for (int s=0;s<16;s++) sv[s] = ld_dev16(gq + 4*(size_t)(s*256 + tid));
            wait_vm();
            #pragma unroll
            for (int s=0;s<16;s++) ((float4*)hs[0])[s*256 + tid] = sv[s];
            __syncthreads();
            for (int q=0;q<4;++q){
                if (q<3){
                    #pragma unroll
                    for (int s=0;s<16;s++) sv[s] = ld_dev16(gq + (size_t)(q+1)*16384 + 4*(size_t)(s*256 + tid));
                }
                const float* hb = hs[q&1];
                const float* Uzq = Uz + q*256;
                const float* Urq = Ur + q*256;
                const float* Uhq = Uh + q*256;
                #pragma unroll 8
                for (int k=0;k<256;++k){
                    float h = hb[k*64 + lane];
                    az = fmaf(h, Uzq[k], az);
                    ar = fmaf(h, Urq[k], ar);
                    ah = fmaf(h, Uhq[k], ah);
                }
                if ((cu>>8) == q) hp = hb[(cu&255)*64 + lane];
                if (q<3){
                    wait_vm();
                    #pragma unroll
                    for (int s=0;s<16;s++) ((float4*)hs[(q+1)&1])[s*256 + tid] = sv[s];
                }
                __syncthreads();
            }
        }
        float z  = fsig_(xz + az + bz);
        float r  = fsig_(xr + ar + br);
        float hh = ftanh_(xh + r*(ah + bh));
        float hnew = z*hp + (1.f - z)*hh;
        st_dev4(hT + (size_t)(cur^1)*65536 + cu*64 + lane, hnew);   // coalesced publish
        hpe[((size_t)lane*TT + t)*HH + cu] = hnew;
        gridbar(bar + (size_t)t*256, sub, 256);
    }
}

// ---------------- persistent decoder: 256 WGs x 512 thr ----------------
// waves 0-3: GRU matmul (unit = wg*4+wave, lane = batch); waves 4-7 on wg<64: attention team b=wg
__global__ __launch_bounds__(512) void k_dec(const float* __restrict__ hpe,
                                             const float* __restrict__ Ut,
                                             const float* __restrict__ b1,
                                             const float* __restrict__ Edec,
                                             const float* __restrict__ scale,
                                             const float* __restrict__ fcW,
                                             const float* __restrict__ fcb,
                                             float* __restrict__ hdT,
                                             float* __restrict__ hdl,
                                             float* __restrict__ out,
                                             int* __restrict__ idx_t,
                                             int* __restrict__ bar,
                                             int* __restrict__ flagidx){
    __shared__ float hs[2][16384];
    __shared__ float ctxs[4][1024];
    __shared__ float edl[4][3][28];
    __shared__ float m_s[4], S_s[4];
    __shared__ int c_a, c_fc, go, cstg;
    int tid = threadIdx.x, wg = blockIdx.x;
    if (tid == 0){ c_a=0; c_fc=0; go=0; cstg=0; }
    __syncthreads();

    if (tid < 256){
        // ============ matmul role ============
        int lane = tid & 63;
        int sub = wg & 15;
        int wv = tid >> 6;
        int cu = __builtin_amdgcn_readfirstlane(wg*4 + wv);
        const float* Uz = Ut + (size_t)cu*HH;
        const float* Ur = Uz + (size_t)HH*HH;
        const float* Uh = Ur + (size_t)HH*HH;
        float bz = b1[cu], br = b1[cu+HH], bh = b1[cu+2*HH];
        // preload this wave's Edec gate rows into LDS (private to this wave)
        for (int tq = lane; tq < 84; tq += 64){
            int g = tq / 28, v = tq - g*28;
            edl[wv][g][v] = Edec[(size_t)v*H3 + cu + g*HH];
        }
        int stgt = 0;
        for (int i=0; i<TT; ++i){
            int cur = i & 1;
            float az=0.f, ar=0.f, ah=0.f, hp=0.f;
            if (i > 0){
                const float* gq = hdT + (size_t)cur*65536;
                float4 sv[16];
                #pragma unroll
                for (int s=0;s<16;s++) sv[s] = ld_dev16(gq + 4*(size_t)(s*256 + tid));
                wait_vm();
                #pragma unroll
                for (int s=0;s<16;s++) ((float4*)hs[0])[s*256 + tid] = sv[s];
                wbar4(&cstg, stgt += 4);
                for (int q=0;q<4;++q){
                    if (q<3){
                        #pragma unroll
                        for (int s=0;s<16;s++) sv[s] = ld_dev16(gq + (size_t)(q+1)*16384 + 4*(size_t)(s*256 + tid));
                    }
                    const float* hb = hs[q&1];
                    const float* Uzq = Uz + q*256;
                    const float* Urq = Ur + q*256;
                    const float* Uhq = Uh + q*256;
                    #pragma unroll 8
                    for (int k=0;k<256;++k){
                        float h = hb[k*64 + lane];
                        az = fmaf(h, Uzq[k], az);
                        ar = fmaf(h, Urq[k], ar);
                        ah = fmaf(h, Uhq[k], ah);
                    }
                    if ((cu>>8) == q) hp = hb[(cu&255)*64 + lane];
                    if (q<3){
                        wait_vm();
                        #pragma unroll
                        for (int s=0;s<16;s++) ((float4*)hs[(q+1)&1])[s*256 + tid] = sv[s];
                    }
                    wbar4(&cstg, stgt += 4);
                }
            }
            // wait for idx(i): single poller + LDS broadcast
            if (tid == 0){
                unsigned gy = 0; int s;
                do {
                    s = 0;
                    #pragma unroll
                    for (int c=0;c<8;c++) s += __hip_atomic_load(flagidx + (size_t)i*128 + c*16, __ATOMIC_RELAXED, AGENT);
                    if (s < 64){ if (++gy > SPIN_CAP) break; __builtin_amdgcn_s_sleep(4); }
                } while (s < 64);
                __hip_atomic_store(&go, i+1, __ATOMIC_RELAXED, WGRP);
            }
            { unsigned gy=0; while (__hip_atomic_load(&go, __ATOMIC_RELAXED, WGRP) < i+1){ if (++gy > SPIN_CAP) break; } }
            asm volatile("" ::: "memory");
            int mi_raw = ld_dev4i(idx_t + (size_t)i*64 + lane);
            wait_vm();
            unsigned mi = (unsigned)mi_raw;
            if (mi > 27u) mi = 0;
            float xz = edl[wv][0][mi];
            float xr = edl[wv][1][mi];
            float xh = edl[wv][2][mi];
            float z  = fsig_(xz + az + bz);
            float r  = fsig_(xr + ar + br);
            float hh = ftanh_(xh + r*(ah + bh));
            float hnew = z*hp + (1.f - z)*hh;
            st_dev4(hdT + (size_t)(cur^1)*65536 + cu*64 + lane, hnew);            // coalesced
            st_dev4(hdl + (size_t)(cur^1)*65536 + (size_t)lane*HH + cu, hnew);    // scattered (unavoidable)
            gridbar(bar + (size_t)i*256, sub, 256);
        }
    } else if (wg < 64){
        // ============ attention team for batch b = wg ============
        int t2 = tid - 256;
        int w = t2 >> 6, lane = t2 & 63, b = wg;
        float sc[16];
        #pragma unroll
        for (int s4=0;s4<4;s4++){
            float4 v = *(const float4*)(scale + lane*16 + s4*4);
            sc[s4*4+0]=v.x; sc[s4*4+1]=v.y; sc[s4*4+2]=v.z; sc[s4*4+3]=v.w;
        }
        int j0 = w*25;
        const float* hpb = hpe + ((size_t)b*TT + j0)*HH + lane*16;
        for (int i=0; i<TT; ++i){
            float q[16];
            if (i == 0){
                #pragma unroll
                for (int d=0;d<16;d++) q[d]=0.f;
            } else {
                const float* hq = hdl + (size_t)(i&1)*65536 + (size_t)b*HH + lane*16;
                float4 q0 = ld_dev16(hq), q1 = ld_dev16(hq+4), q2 = ld_dev16(hq+8), q3 = ld_dev16(hq+12);
                wait_vm();
                q[0]=q0.x;q[1]=q0.y;q[2]=q0.z;q[3]=q0.w;
                q[4]=q1.x;q[5]=q1.y;q[6]=q1.z;q[7]=q1.w;
                q[8]=q2.x;q[9]=q2.y;q[10]=q2.z;q[11]=q2.w;
                q[12]=q3.x;q[13]=q3.y;q[14]=q3.z;q[15]=q3.w;
            }
            if (w == 0){
                if (i > 0){
                    float acc[NOUT];
                    #pragma unroll
                    for (int o=0;o<NOUT;o++) acc[o]=0.f;
                    float cv[16];
                    #pragma unroll
                    for (int s4=0;s4<4;s4++){
                        float4 c0 = ((const float4*)ctxs[0])[lane*4+s4];
                        float4 c1 = ((const float4*)ctxs[1])[lane*4+s4];
                        float4 c2 = ((const float4*)ctxs[2])[lane*4+s4];
                        float4 c3 = ((const float4*)ctxs[3])[lane*4+s4];
                        cv[s4*4+0]=c0.x+c1.x+c2.x+c3.x;
                        cv[s4*4+1]=c0.y+c1.y+c2.y+c3.y;
                        cv[s4*4+2]=c0.z+c1.z+c2.z+c3.z;
                        cv[s4*4+3]=c0.w+c1.w+c2.w+c3.w;
                    }
                    #pragma unroll
                    for (int dd=0;dd<16;++dd){
                        int d = lane*16 + dd;
                        const float* w0p = fcW + (size_t)d*NOUT;
                        const float* w1p = fcW + (size_t)(d+HH)*NOUT;
                        float hv=q[dd], cvv=cv[dd];
                        #pragma unroll
                        for (int o=0;o<NOUT;o++) acc[o] = fmaf(hv, w0p[o], fmaf(cvv, w1p[o], acc[o]));
                    }
                    #pragma unroll
                    for (int o=0;o<NOUT;o++){
                        #pragma unroll
                        for (int m=1;m<64;m<<=1) acc[o] += __shfl_xor(acc[o], m);
                    }
                    float bv=-3.0e38f; int bi=0;
                    #pragma unroll
                    for (int o=0;o<NOUT;o++){
                        float p = acc[o] + fcb[o];
                        acc[o] = p;
                        if (p > bv){ bv = p; bi = o; }
                    }
                    float vout = 0.f;
                    #pragma unroll
                    for (int o=0;o<NOUT;o++) if (lane == o) vout = acc[o];
                    if (lane < NOUT) out[((size_t)b*TT + (i-1))*NOUT + lane] = vout;
                    if (lane == 0){
                        __hip_atomic_store(idx_t + (size_t)i*64 + b, bi, __ATOMIC_RELAXED, AGENT);
                        asm volatile("s_waitcnt vmcnt(0)" ::: "memory");
                    }
                }
                if (lane == 0){
                    __hip_atomic_fetch_add(flagidx + (size_t)i*128 + (b&7)*16, 1, __ATOMIC_RELAXED, AGENT);
                    __hip_atomic_fetch_add(&c_fc, 1, __ATOMIC_RELAXED, WGRP);
                }
            }
            // ---- online-softmax, hpe read once, next-key prefetch double-buffer ----
            float m = -3.0e38f, S = 0.f;
            float a[16];
            #pragma unroll
            for (int d=0;d<16;d++) a[d]=0.f;
            float4 n0 = *(const float4*)(hpb);
            float4 n1 = *(const float4*)(hpb+4);
            float4 n2 = *(const float4*)(hpb+8);
            float4 n3 = *(const float4*)(hpb+12);
            for (int jj=0;jj<25;jj++){
                float4 v0=n0, v1=n1, v2=n2, v3=n3;
                if (jj < 24){
                    const float* hpn = hpb + (size_t)(jj+1)*HH;
                    n0 = *(const float4*)(hpn);
                    n1 = *(const float4*)(hpn+4);
                    n2 = *(const float4*)(hpn+8);
                    n3 = *(const float4*)(hpn+12);
                }
                float va[16];
                va[0]=v0.x;va[1]=v0.y;va[2]=v0.z;va[3]=v0.w;
                va[4]=v1.x;va[5]=v1.y;va[6]=v1.z;va[7]=v1.w;
                va[8]=v2.x;va[9]=v2.y;va[10]=v2.z;va[11]=v2.w;
                va[12]=v3.x;va[13]=v3.y;va[14]=v3.z;va[15]=v3.w;
                float s = 0.f;
                #pragma unroll
                for (int d=0;d<16;d++) s += sc[d]*ftanh_(q[d] + va[d]);
                #pragma unroll
                for (int mm=1;mm<64;mm<<=1) s += __shfl_xor(s, mm);
                float mn = fmaxf(m, s);
                float fold = __expf(m - mn);
                float e = __expf(s - mn);
                S = S*fold + e;
                #pragma unroll
                for (int d=0;d<16;d++) a[d] = a[d]*fold + e*va[d];
                m = mn;
            }
            if (lane == 0){ m_s[w] = m; S_s[w] = S; }
            asm volatile("s_waitcnt lgkmcnt(0)" ::: "memory");
            if (lane == 0) __hip_atomic_fetch_add(&c_a, 1, __ATOMIC_RELAXED, WGRP);
            { unsigned gy=0; while (__hip_atomic_load(&c_a, __ATOMIC_RELAXED, WGRP) < 4*(i+1)){ if (++gy > SPIN_CAP) break; } }
            asm volatile("" ::: "memory");
            float M = fmaxf(fmaxf(m_s[0],m_s[1]), fmaxf(m_s[2],m_s[3]));
            float St = S_s[0]*__expf(m_s[0]-M) + S_s[1]*__expf(m_s[1]-M)
                     + S_s[2]*__expf(m_s[2]-M) + S_s[3]*__expf(m_s[3]-M);
            float g = __expf(m - M) * frcp_(St);
            // wait until fc consumed ctxs of step i-1
            { unsigned gy=0; while (__hip_atomic_load(&c_fc, __ATOMIC_RELAXED, WGRP) < i+1){ if (++gy > SPIN_CAP) break; } }
            asm volatile("" ::: "memory");
            #pragma unroll
            for (int s4=0;s4<4;s4++){
                float4 o4;
                o4.x=a[s4*4+0]*g; o4.y=a[s4*4+1]*g;
                o4.z=a[s4*4+2]*g; o4.w=a[s4*4+3]*g;
                ((float4*)ctxs[w])[lane*4 + s4] = o4;
            }
            gridbar(bar + (size_t)i*256, wg & 15, 256);
        }
        // epilogue: p(99) = [hd(100), ctx(99)] @ fc ; hd(100) is in hdl slot 0
        if (w == 0){
            const float* hq = hdl + (size_t)b*HH + lane*16;
            float4 q0 = ld_dev16(hq), q1 = ld_dev16(hq+4), q2 = ld_dev16(hq+8), q3 = ld_dev16(hq+12);
            wait_vm();
            float q[16];
            q[0]=q0.x;q[1]=q0.y;q[2]=q0.z;q[3]=q0.w;
            q[4]=q1.x;q[5]=q1.y;q[6]=q1.z;q[7]=q1.w;
            q[8]=q2.x;q[9]=q2.y;q[10]=q2.z;q[11]=q2.w;
            q[12]=q3.x;q[13]=q3.y;q[14]=q3.z;q[15]=q3.w;
            float acc[NOUT];
            #pragma unroll
            for (int o=0;o<NOUT;o++) acc[o]=0.f;
            float cv[16];
            #pragma unroll
            for (int s4=0;s4<4;s4++){
                float4 c0 = ((const float4*)ctxs[0])[lane*4+s4];
                float4 c1 = ((const float4*)ctxs[1])[lane*4+s4];
                float4 c2 = ((const float4*)ctxs[2])[lane*4+s4];
                float4 c3 = ((const float4*)ctxs[3])[lane*4+s4];
                cv[s4*4+0]=c0.x+c1.x+c2.x+c3.x;
                cv[s4*4+1]=c0.y+c1.y+c2.y+c3.y;
                cv[s4*4+2]=c0.z+c1.z+c2.z+c3.z;
                cv[s4*4+3]=c0.w+c1.w+c2.w+c3.w;
            }
            #pragma unroll
            for (int dd=0;dd<16;++dd){
                int d = lane*16 + dd;
                const float* w0p = fcW + (size_t)d*NOUT;
                const float* w1p = fcW + (size_t)(d+HH)*NOUT;
                float hv=q[dd], cvv=cv[dd];
                #pragma unroll
                for (int o=0;o<NOUT;o++) acc[o] = fmaf(hv, w0p[o], fmaf(cvv, w1p[o], acc[o]));
            }
            #pragma unroll
            for (int o=0;o<NOUT;o++){
                #pragma unroll
                for (int m=1;m<64;m<<=1) acc[o] += __shfl_xor(acc[o], m);
            }
            float vout = 0.f;
            #pragma unroll
            for (int o=0;o<NOUT;o++) if (lane == o) vout = acc[o] + fcb[o];
            if (lane < NOUT) out[((size_t)b*TT + 99)*NOUT + lane] = vout;
        }
    } else {
        for (int i=0;i<TT;++i) gridbar(bar + (size_t)i*256, wg & 15, 256);
    }
}

extern "C" void kernel_launch(void* const* d_in, const int* in_sizes, int n_in,
                              void* d_out, int out_size, void* d_ws, size_t ws_size,
                              hipStream_t stream){
    (void)in_sizes; (void)n_in; (void)out_size; (void)ws_size;
    const float* x     = (const float*)d_in[0];
    const float* encW  = (const float*)d_in[1];
    const float* encU  = (const float*)d_in[2];
    const float* encb  = (const float*)d_in[3];
    const float* scale = (const float*)d_in[4];
    const float* emb   = (const float*)d_in[5];
    const float* decW  = (const float*)d_in[6];
    const float* decU  = (const float*)d_in[7];
    const float* decb  = (const float*)d_in[8];
    const float* fcW   = (const float*)d_in[9];
    const float* fcb   = (const float*)d_in[10];
    float* out = (float*)d_out;
    float* ws  = (float*)d_ws;

    // ~132.2 MB total (round-4/8/10-proven footprint)
    float* MXT   = ws;                        // 19,660,800 (encoder phase only)
    float* hdT   = MXT;                       // dec overlay: 2*65,536 ping-pong [k][b]
    float* hdl   = MXT + 131072;              // dec overlay: 2*65,536 ping-pong [b][k]
    float* encUt = MXT   + 19660800;          // 3,145,728
    float* decUt = encUt + 3145728;           // 3,145,728
    float* hpe   = decUt + 3145728;           // 6,553,600
    float* Edec  = hpe   + 6553600;           // 86,016
    float* hT    = Edec  + 86016;             // 2*65,536 ping-pong [k][b] (encoder)
    int*   ib    = (int*)(hT + 131072);
    int*   bar_enc = ib;                      // 100*256
    int*   bar_dec = ib + 25600;              // 100*256
    int*   flagidx = ib + 51200;              // 100*128
    int*   idx_t   = ib + 64000;              // 100*64   (total 70,400 ints)

    const float* encb1 = encb + H3;
    const float* decb1 = decb + H3;

    k_init<<<276,256,0,stream>>>(ib, 70400);
    k_transpose<<<dim3(96,32,2),256,0,stream>>>(encU, decU, encUt, decUt);
    k_edec<<<336,256,0,stream>>>(emb, decW, decb, Edec);
    k_mxgemm<<<dim3(48,100),256,0,stream>>>(x, encW, encb, MXT);
    k_enc<<<256,256,0,stream>>>(MXT, encUt, encb1, hpe, hT, bar_enc);
    k_dec<<<256,512,0,stream>>>(hpe, decUt, decb1, Edec, scale, fcW, fcb,
                                hdT, hdl, out, idx_t, bar_dec, flagidx);
}

// Round 13
// 10068.126 us; speedup vs baseline: 1.7879x; 1.0072x over previous
//
#include <hip/hip_runtime.h>

#define TT 100
#define HH 1024
#define H3 3072
#define NOUT 28

#define AGENT __HIP_MEMORY_SCOPE_AGENT
#define WGRP  __HIP_MEMORY_SCOPE_WORKGROUP
#define SPIN_CAP (1u<<20)

typedef float f32x4 __attribute__((ext_vector_type(4)));

__device__ __forceinline__ float frcp_(float x){ return __builtin_amdgcn_rcpf(x); }
__device__ __forceinline__ float fsig_(float x){ return frcp_(1.0f + __expf(-x)); }
__device__ __forceinline__ float ftanh_(float x){ return 1.0f - 2.0f*frcp_(__expf(2.0f*x) + 1.0f); }
__device__ __forceinline__ void wait_vm(){ asm volatile("s_waitcnt vmcnt(0)" ::: "memory"); }

// device-coherent 16B load: bypass L1+L2, read at the coherence point
__device__ __forceinline__ float4 ld_dev16(const float* p){
    float4 v;
    asm volatile("global_load_dwordx4 %0, %1, off sc0 sc1" : "=v"(v) : "v"(p) : "memory");
    return v;
}
// device-coherent 4B load (coalesces across a wave)
__device__ __forceinline__ int ld_dev4i(const int* p){
    int v;
    asm volatile("global_load_dword %0, %1, off sc0 sc1" : "=v"(v) : "v"(p) : "memory");
    return v;
}
// device-coherent stores: write-through to coherence point
__device__ __forceinline__ void st_dev4(float* p, float v){
    asm volatile("global_store_dword %0, %1, off sc0 sc1" :: "v"(p), "v"(v) : "memory");
}
__device__ __forceinline__ void st_dev16(float* p, f32x4 v){
    asm volatile("global_store_dwordx4 %0, %1, off sc0 sc1" :: "v"(p), "v"(v) : "memory");
}
__device__ __forceinline__ unsigned aload4(const int* p){
    return (unsigned)__hip_atomic_load(p, __ATOMIC_RELAXED, AGENT);
}

// grid barrier: 16 padded sub-counters per slot (slot stride = 256 ints), relaxed only.
// __syncthreads drains vmcnt -> all sc0sc1 publishes complete before arrival.
__device__ __forceinline__ void gridbar(int* slot, int sub, int target){
    __syncthreads();
    if (threadIdx.x == 0){
        __hip_atomic_fetch_add(slot + sub*16, 1, __ATOMIC_RELAXED, AGENT);
        unsigned gy = 0; int s;
        do {
            s = 0;
            #pragma unroll
            for (int c=0;c<16;c++) s += __hip_atomic_load(slot + c*16, __ATOMIC_RELAXED, AGENT);
            if (s < target){ if (++gy > SPIN_CAP) break; __builtin_amdgcn_s_sleep(4); }
        } while (s < target);
    }
    __syncthreads();
}

// barrier among the 4 matmul waves only (LDS counter, monotonic target), capped
__device__ __forceinline__ void wbar4(int* c, int tgt){
    asm volatile("s_waitcnt lgkmcnt(0)" ::: "memory");
    if ((threadIdx.x & 63) == 0) __hip_atomic_fetch_add(c, 1, __ATOMIC_RELAXED, WGRP);
    unsigned gy = 0;
    while (__hip_atomic_load(c, __ATOMIC_RELAXED, WGRP) < tgt){ if (++gy > SPIN_CAP) break; }
    asm volatile("" ::: "memory");
}

// ---------------- init: zero control ints ----------------
__global__ void k_init(int* ib, int n){
    int g = blockIdx.x*256 + threadIdx.x;
    if (g < n) ib[g] = 0;
}

// ---------------- transpose U [1024][3072] -> Ut [3072][1024] ----------------
__global__ __launch_bounds__(256) void k_transpose(const float* __restrict__ U0,
                                                   const float* __restrict__ U1,
                                                   float* __restrict__ T0,
                                                   float* __restrict__ T1){
    const float* U = blockIdx.z ? U1 : U0;
    float*       T = blockIdx.z ? T1 : T0;
    __shared__ float tile[32][33];
    int tx = threadIdx.x & 31, ty = threadIdx.x >> 5;
    int j0 = blockIdx.x*32, k0 = blockIdx.y*32;
    #pragma unroll
    for (int q=0;q<4;q++){
        int kr = ty + q*8;
        tile[kr][tx] = U[(size_t)(k0+kr)*H3 + j0 + tx];
    }
    __syncthreads();
    #pragma unroll
    for (int q=0;q<4;q++){
        int jr = ty + q*8;
        T[(size_t)(j0+jr)*HH + k0 + tx] = tile[tx][jr];
    }
}

// ---------------- Edec[28][3072] = emb @ decW + decb[0] ----------------
__global__ __launch_bounds__(256) void k_edec(const float* __restrict__ emb,
                                              const float* __restrict__ W,
                                              const float* __restrict__ b0,
                                              float* __restrict__ E){
    int gid = blockIdx.x*256 + threadIdx.x;   // 28*3072 = 86016
    int v = gid / H3, j = gid - v*H3;
    float acc = b0[j];
    const float* er = emb + (size_t)v*HH;
    #pragma unroll 4
    for (int k=0;k<HH;k++) acc = fmaf(er[k], W[(size_t)k*H3 + j], acc);
    E[gid] = acc;
}

// ---------------- MXT[t][col][b] = (x2d @ encW + encb[0]) transposed ----------------
__global__ __launch_bounds__(256) void k_mxgemm(const float* __restrict__ A,
                                                const float* __restrict__ W,
                                                const float* __restrict__ b0,
                                                float* __restrict__ MXT){
    __shared__ float aT[32*68];
    __shared__ float bL[32*68];
    int tid = threadIdx.x;
    int row0 = blockIdx.y*64, col0 = blockIdx.x*64;
    int arow = tid>>2, acs = (tid&3)*4;
    int bk   = tid>>3, bcs = (tid&7)*4;
    int ty = tid>>4, tx = tid&15;
    float acc[4][4] = {};
    for (int kk=0; kk<HH; kk+=32){
        #pragma unroll
        for (int i=0;i<2;i++){
            int c = acs + i*16;
            float4 v = *(const float4*)(A + (size_t)(row0+arow)*HH + kk + c);
            aT[(c+0)*68 + arow] = v.x; aT[(c+1)*68 + arow] = v.y;
            aT[(c+2)*68 + arow] = v.z; aT[(c+3)*68 + arow] = v.w;
        }
        #pragma unroll
        for (int i=0;i<2;i++){
            int c = bcs + i*32;
            float4 v = *(const float4*)(W + (size_t)(kk+bk)*H3 + col0 + c);
            *(float4*)(bL + bk*68 + c) = v;
        }
        __syncthreads();
        #pragma unroll
        for (int k=0;k<32;k++){
            float4 a4 = *(const float4*)(aT + k*68 + ty*4);
            float4 b4 = *(const float4*)(bL + k*68 + tx*4);
            acc[0][0]=fmaf(a4.x,b4.x,acc[0][0]); acc[0][1]=fmaf(a4.x,b4.y,acc[0][1]);
            acc[0][2]=fmaf(a4.x,b4.z,acc[0][2]); acc[0][3]=fmaf(a4.x,b4.w,acc[0][3]);
            acc[1][0]=fmaf(a4.y,b4.x,acc[1][0]); acc[1][1]=fmaf(a4.y,b4.y,acc[1][1]);
            acc[1][2]=fmaf(a4.y,b4.z,acc[1][2]); acc[1][3]=fmaf(a4.y,b4.w,acc[1][3]);
            acc[2][0]=fmaf(a4.z,b4.x,acc[2][0]); acc[2][1]=fmaf(a4.z,b4.y,acc[2][1]);
            acc[2][2]=fmaf(a4.z,b4.z,acc[2][2]); acc[2][3]=fmaf(a4.z,b4.w,acc[2][3]);
            acc[3][0]=fmaf(a4.w,b4.x,acc[3][0]); acc[3][1]=fmaf(a4.w,b4.y,acc[3][1]);
            acc[3][2]=fmaf(a4.w,b4.z,acc[3][2]); acc[3][3]=fmaf(a4.w,b4.w,acc[3][3]);
        }
        __syncthreads();
    }
    float4 bb = *(const float4*)(b0 + col0 + tx*4);
    #pragma unroll
    for (int i=0;i<4;i++){
        int r = row0 + ty*4 + i;
        int bq = r / 100; int tq = r - bq*100;
        float v0 = acc[i][0] + bb.x, v1 = acc[i][1] + bb.y;
        float v2 = acc[i][2] + bb.z, v3 = acc[i][3] + bb.w;
        float* dst = MXT + ((size_t)tq*H3 + col0 + tx*4)*64 + bq;
        dst[0]   = v0; dst[64]  = v1; dst[128] = v2; dst[192] = v3;
    }
}

// ---------------- persistent encoder: 256 WGs x 256 thr ----------------
__global__ __launch_bounds__(256) void k_enc(const float* __restrict__ MXT,
                                             const float* __restrict__ Ut,
                                             const float* __restrict__ b1,
                                             float* __restrict__ hpe,
                                             float* __restrict__ hT,
                                             int* __restrict__ bar){
    __shared__ float hs[2][16384];
    int tid = threadIdx.x, lane = tid & 63;
    int wg = blockIdx.x;
    int sub = wg & 15;
    int cu = __builtin_amdgcn_readfirstlane(wg*4 + (tid>>6));
    const float* Uz = Ut + (size_t)cu*HH;
    const float* Ur = Uz + (size_t)HH*HH;
    const float* Uh = Ur + (size_t)HH*HH;
    float bz = b1[cu], br = b1[cu+HH], bh = b1[cu+2*HH];
    for (int t=0; t<TT; ++t){
        int cur = t & 1;
        const float* mx = MXT + (size_t)t*H3*64;
        float xz = mx[(size_t)cu*64 + lane];
        float xr = mx[(size_t)(cu+HH)*64 + lane];
        float xh = mx[(size_t)(cu+2*HH)*64 + lane];
        float az=0.f, ar=0.f, ah=0.f, hp=0.f;
        if (t > 0){
            const float* gq = hT + (size_t)cur*65536;
            float4 sv[16];
            #pragma unroll
            for (int s=0;s<16;s++) sv[s] = ld_dev16(gq + 4*(size_t)(s*256 + tid));
            wait_vm();
            #pragma unroll
            for (int s=0;s<16;s++) ((float4*)hs[0])[s*256 + tid] = sv[s];
            __syncthreads();
            for (int q=0;q<4;++q){
                if (q<3){
                    #pragma unroll
                    for (int s=0;s<16;s++) sv[s] = ld_dev16(gq + (size_t)(q+1)*16384 + 4*(size_t)(s*256 + tid));
                }
                const float* hb = hs[q&1];
                const float* Uzq = Uz + q*256;
                const float* Urq = Ur + q*256;
                const float* Uhq = Uh + q*256;
                #pragma unroll 8
                for (int k=0;k<256;++k){
                    float h = hb[k*64 + lane];
                    az = fmaf(h, Uzq[k], az);
                    ar = fmaf(h, Urq[k], ar);
                    ah = fmaf(h, Uhq[k], ah);
                }
                if ((cu>>8) == q) hp = hb[(cu&255)*64 + lane];
                if (q<3){
                    wait_vm();
                    #pragma unroll
                    for (int s=0;s<16;s++) ((float4*)hs[(q+1)&1])[s*256 + tid] = sv[s];
                }
                __syncthreads();
            }
        }
        float z  = fsig_(xz + az + bz);
        float r  = fsig_(xr + ar + br);
        float hh = ftanh_(xh + r*(ah + bh));
        float hnew = z*hp + (1.f - z)*hh;
        st_dev4(hT + (size_t)(cur^1)*65536 + cu*64 + lane, hnew);   // coalesced publish
        hpe[((size_t)lane*TT + t)*HH + cu] = hnew;
        gridbar(bar + (size_t)t*256, sub, 256);
    }
}

// ---------------- persistent decoder: 256 WGs x 512 thr ----------------
// waves 0-3: GRU matmul (unit = wg*4+wave, lane = batch); waves 4-7 on wg<64: attention team b=wg
__global__ __launch_bounds__(512) void k_dec(const float* __restrict__ hpe,
                                             const float* __restrict__ Ut,
                                             const float* __restrict__ b1,
                                             const float* __restrict__ Edec,
                                             const float* __restrict__ scale,
                                             const float* __restrict__ fcW,
                                             const float* __restrict__ fcb,
                                             float* __restrict__ hdT,
                                             float* __restrict__ hdl,
                                             float* __restrict__ out,
                                             int* __restrict__ idx_t,
                                             int* __restrict__ bar,
                                             int* __restrict__ flagidx){
    __shared__ float hs[2][16384];
    __shared__ float ctxs[4][1024];
    __shared__ float edl[4][3][28];
    __shared__ float trs[256];
    __shared__ float m_s[4], S_s[4];
    __shared__ int c_a, c_fc, go, cstg;
    int tid = threadIdx.x, wg = blockIdx.x;
    if (tid == 0){ c_a=0; c_fc=0; go=0; cstg=0; }
    __syncthreads();

    if (tid < 256){
        // ============ matmul role ============
        int lane = tid & 63;
        int sub = wg & 15;
        int wv = tid >> 6;
        int cu = __builtin_amdgcn_readfirstlane(wg*4 + wv);
        const float* Uz = Ut + (size_t)cu*HH;
        const float* Ur = Uz + (size_t)HH*HH;
        const float* Uh = Ur + (size_t)HH*HH;
        float bz = b1[cu], br = b1[cu+HH], bh = b1[cu+2*HH];
        // preload this wave's Edec gate rows into LDS (private to this wave)
        for (int tq = lane; tq < 84; tq += 64){
            int g = tq / 28, v = tq - g*28;
            edl[wv][g][v] = Edec[(size_t)v*H3 + cu + g*HH];
        }
        int stgt = 0;
        for (int i=0; i<TT; ++i){
            int cur = i & 1;
            float az=0.f, ar=0.f, ah=0.f, hp=0.f;
            if (i > 0){
                const float* gq = hdT + (size_t)cur*65536;
                float4 sv[16];
                #pragma unroll
                for (int s=0;s<16;s++) sv[s] = ld_dev16(gq + 4*(size_t)(s*256 + tid));
                wait_vm();
                #pragma unroll
                for (int s=0;s<16;s++) ((float4*)hs[0])[s*256 + tid] = sv[s];
                wbar4(&cstg, stgt += 4);
                for (int q=0;q<4;++q){
                    if (q<3){
                        #pragma unroll
                        for (int s=0;s<16;s++) sv[s] = ld_dev16(gq + (size_t)(q+1)*16384 + 4*(size_t)(s*256 + tid));
                    }
                    const float* hb = hs[q&1];
                    const float* Uzq = Uz + q*256;
                    const float* Urq = Ur + q*256;
                    const float* Uhq = Uh + q*256;
                    #pragma unroll 8
                    for (int k=0;k<256;++k){
                        float h = hb[k*64 + lane];
                        az = fmaf(h, Uzq[k], az);
                        ar = fmaf(h, Urq[k], ar);
                        ah = fmaf(h, Uhq[k], ah);
                    }
                    if ((cu>>8) == q) hp = hb[(cu&255)*64 + lane];
                    if (q<3){
                        wait_vm();
                        #pragma unroll
                        for (int s=0;s<16;s++) ((float4*)hs[(q+1)&1])[s*256 + tid] = sv[s];
                    }
                    wbar4(&cstg, stgt += 4);
                }
            }
            // wait for idx(i): single poller + LDS broadcast
            if (tid == 0){
                unsigned gy = 0; int s;
                do {
                    s = 0;
                    #pragma unroll
                    for (int c=0;c<8;c++) s += __hip_atomic_load(flagidx + (size_t)i*128 + c*16, __ATOMIC_RELAXED, AGENT);
                    if (s < 64){ if (++gy > SPIN_CAP) break; __builtin_amdgcn_s_sleep(4); }
                } while (s < 64);
                __hip_atomic_store(&go, i+1, __ATOMIC_RELAXED, WGRP);
            }
            { unsigned gy=0; while (__hip_atomic_load(&go, __ATOMIC_RELAXED, WGRP) < i+1){ if (++gy > SPIN_CAP) break; } }
            asm volatile("" ::: "memory");
            int mi_raw = ld_dev4i(idx_t + (size_t)i*64 + lane);
            wait_vm();
            unsigned mi = (unsigned)mi_raw;
            if (mi > 27u) mi = 0;
            float xz = edl[wv][0][mi];
            float xr = edl[wv][1][mi];
            float xh = edl[wv][2][mi];
            float z  = fsig_(xz + az + bz);
            float r  = fsig_(xr + ar + br);
            float hh = ftanh_(xh + r*(ah + bh));
            float hnew = z*hp + (1.f - z)*hh;
            st_dev4(hdT + (size_t)(cur^1)*65536 + cu*64 + lane, hnew);   // coalesced
            // hdl publish: LDS transpose -> wave 0 stores 64 x dwordx4 (coalesced lines)
            trs[lane*4 + wv] = hnew;
            wbar4(&cstg, stgt += 4);
            if (wv == 0){
                f32x4 h4 = *(const f32x4*)(trs + lane*4);
                st_dev16(hdl + (size_t)(cur^1)*65536 + (size_t)lane*HH + wg*4, h4);
            }
            gridbar(bar + (size_t)i*256, sub, 256);
        }
    } else if (wg < 64){
        // ============ attention team for batch b = wg ============
        int t2 = tid - 256;
        int w = t2 >> 6, lane = t2 & 63, b = wg;
        float sc[16];
        #pragma unroll
        for (int s4=0;s4<4;s4++){
            float4 v = *(const float4*)(scale + lane*16 + s4*4);
            sc[s4*4+0]=v.x; sc[s4*4+1]=v.y; sc[s4*4+2]=v.z; sc[s4*4+3]=v.w;
        }
        int j0 = w*25;
        const float* hpb = hpe + ((size_t)b*TT + j0)*HH + lane*16;
        for (int i=0; i<TT; ++i){
            float q[16];
            if (i == 0){
                #pragma unroll
                for (int d=0;d<16;d++) q[d]=0.f;
            } else {
                const float* hq = hdl + (size_t)(i&1)*65536 + (size_t)b*HH + lane*16;
                float4 q0 = ld_dev16(hq), q1 = ld_dev16(hq+4), q2 = ld_dev16(hq+8), q3 = ld_dev16(hq+12);
                wait_vm();
                q[0]=q0.x;q[1]=q0.y;q[2]=q0.z;q[3]=q0.w;
                q[4]=q1.x;q[5]=q1.y;q[6]=q1.z;q[7]=q1.w;
                q[8]=q2.x;q[9]=q2.y;q[10]=q2.z;q[11]=q2.w;
                q[12]=q3.x;q[13]=q3.y;q[14]=q3.z;q[15]=q3.w;
            }
            if (w == 0){
                if (i > 0){
                    float acc[NOUT];
                    #pragma unroll
                    for (int o=0;o<NOUT;o++) acc[o]=0.f;
                    float cv[16];
                    #pragma unroll
                    for (int s4=0;s4<4;s4++){
                        float4 c0 = ((const float4*)ctxs[0])[lane*4+s4];
                        float4 c1 = ((const float4*)ctxs[1])[lane*4+s4];
                        float4 c2 = ((const float4*)ctxs[2])[lane*4+s4];
                        float4 c3 = ((const float4*)ctxs[3])[lane*4+s4];
                        cv[s4*4+0]=c0.x+c1.x+c2.x+c3.x;
                        cv[s4*4+1]=c0.y+c1.y+c2.y+c3.y;
                        cv[s4*4+2]=c0.z+c1.z+c2.z+c3.z;
                        cv[s4*4+3]=c0.w+c1.w+c2.w+c3.w;
                    }
                    #pragma unroll
                    for (int dd=0;dd<16;++dd){
                        int d = lane*16 + dd;
                        const float* w0p = fcW + (size_t)d*NOUT;
                        const float* w1p = fcW + (size_t)(d+HH)*NOUT;
                        float hv=q[dd], cvv=cv[dd];
                        #pragma unroll
                        for (int o=0;o<NOUT;o++) acc[o] = fmaf(hv, w0p[o], fmaf(cvv, w1p[o], acc[o]));
                    }
                    #pragma unroll
                    for (int o=0;o<NOUT;o++){
                        #pragma unroll
                        for (int m=1;m<64;m<<=1) acc[o] += __shfl_xor(acc[o], m);
                    }
                    float bv=-3.0e38f; int bi=0;
                    #pragma unroll
                    for (int o=0;o<NOUT;o++){
                        float p = acc[o] + fcb[o];
                        acc[o] = p;
                        if (p > bv){ bv = p; bi = o; }
                    }
                    float vout = 0.f;
                    #pragma unroll
                    for (int o=0;o<NOUT;o++) if (lane == o) vout = acc[o];
                    if (lane < NOUT) out[((size_t)b*TT + (i-1))*NOUT + lane] = vout;
                    if (lane == 0){
                        __hip_atomic_store(idx_t + (size_t)i*64 + b, bi, __ATOMIC_RELAXED, AGENT);
                        asm volatile("s_waitcnt vmcnt(0)" ::: "memory");
                    }
                }
                if (lane == 0){
                    __hip_atomic_fetch_add(flagidx + (size_t)i*128 + (b&7)*16, 1, __ATOMIC_RELAXED, AGENT);
                    __hip_atomic_fetch_add(&c_fc, 1, __ATOMIC_RELAXED, WGRP);
                }
            }
            // ---- online-softmax, hpe read once, next-key prefetch double-buffer ----
            float m = -3.0e38f, S = 0.f;
            float a[16];
            #pragma unroll
            for (int d=0;d<16;d++) a[d]=0.f;
            float4 n0 = *(const float4*)(hpb);
            float4 n1 = *(const float4*)(hpb+4);
            float4 n2 = *(const float4*)(hpb+8);
            float4 n3 = *(const float4*)(hpb+12);
            for (int jj=0;jj<25;jj++){
                float4 v0=n0, v1=n1, v2=n2, v3=n3;
                if (jj < 24){
                    const float* hpn = hpb + (size_t)(jj+1)*HH;
                    n0 = *(const float4*)(hpn);
                    n1 = *(const float4*)(hpn+4);
                    n2 = *(const float4*)(hpn+8);
                    n3 = *(const float4*)(hpn+12);
                }
                float va[16];
                va[0]=v0.x;va[1]=v0.y;va[2]=v0.z;va[3]=v0.w;
                va[4]=v1.x;va[5]=v1.y;va[6]=v1.z;va[7]=v1.w;
                va[8]=v2.x;va[9]=v2.y;va[10]=v2.z;va[11]=v2.w;
                va[12]=v3.x;va[13]=v3.y;va[14]=v3.z;va[15]=v3.w;
                float s = 0.f;
                #pragma unroll
                for (int d=0;d<16;d++) s += sc[d]*ftanh_(q[d] + va[d]);
                #pragma unroll
                for (int mm=1;mm<64;mm<<=1) s += __shfl_xor(s, mm);
                float mn = fmaxf(m, s);
                float fold = __expf(m - mn);
                float e = __expf(s - mn);
                S = S*fold + e;
                #pragma unroll
                for (int d=0;d<16;d++) a[d] = a[d]*fold + e*va[d];
                m = mn;
            }
            if (lane == 0){ m_s[w] = m; S_s[w] = S; }
            asm volatile("s_waitcnt lgkmcnt(0)" ::: "memory");
            if (lane == 0) __hip_atomic_fetch_add(&c_a, 1, __ATOMIC_RELAXED, WGRP);
            { unsigned gy=0; while (__hip_atomic_load(&c_a, __ATOMIC_RELAXED, WGRP) < 4*(i+1)){ if (++gy > SPIN_CAP) break; } }
            asm volatile("" ::: "memory");
            float M = fmaxf(fmaxf(m_s[0],m_s[1]), fmaxf(m_s[2],m_s[3]));
            float St = S_s[0]*__expf(m_s[0]-M) + S_s[1]*__expf(m_s[1]-M)
                     + S_s[2]*__expf(m_s[2]-M) + S_s[3]*__expf(m_s[3]-M);
            float g = __expf(m - M) * frcp_(St);
            // wait until fc consumed ctxs of step i-1
            { unsigned gy=0; while (__hip_atomic_load(&c_fc, __ATOMIC_RELAXED, WGRP) < i+1){ if (++gy > SPIN_CAP) break; } }
            asm volatile("" ::: "memory");
            #pragma unroll
            for (int s4=0;s4<4;s4++){
                float4 o4;
                o4.x=a[s4*4+0]*g; o4.y=a[s4*4+1]*g;
                o4.z=a[s4*4+2]*g; o4.w=a[s4*4+3]*g;
                ((float4*)ctxs[w])[lane*4 + s4] = o4;
            }
            gridbar(bar + (size_t)i*256, wg & 15, 256);
        }
        // epilogue: p(99) = [hd(100), ctx(99)] @ fc ; hd(100) is in hdl slot 0
        if (w == 0){
            const float* hq = hdl + (size_t)b*HH + lane*16;
            float4 q0 = ld_dev16(hq), q1 = ld_dev16(hq+4), q2 = ld_dev16(hq+8), q3 = ld_dev16(hq+12);
            wait_vm();
            float q[16];
            q[0]=q0.x;q[1]=q0.y;q[2]=q0.z;q[3]=q0.w;
            q[4]=q1.x;q[5]=q1.y;q[6]=q1.z;q[7]=q1.w;
            q[8]=q2.x;q[9]=q2.y;q[10]=q2.z;q[11]=q2.w;
            q[12]=q3.x;q[13]=q3.y;q[14]=q3.z;q[15]=q3.w;
            float acc[NOUT];
            #pragma unroll
            for (int o=0;o<NOUT;o++) acc[o]=0.f;
            float cv[16];
            #pragma unroll
            for (int s4=0;s4<4;s4++){
                float4 c0 = ((const float4*)ctxs[0])[lane*4+s4];
                float4 c1 = ((const float4*)ctxs[1])[lane*4+s4];
                float4 c2 = ((const float4*)ctxs[2])[lane*4+s4];
                float4 c3 = ((const float4*)ctxs[3])[lane*4+s4];
                cv[s4*4+0]=c0.x+c1.x+c2.x+c3.x;
                cv[s4*4+1]=c0.y+c1.y+c2.y+c3.y;
                cv[s4*4+2]=c0.z+c1.z+c2.z+c3.z;
                cv[s4*4+3]=c0.w+c1.w+c2.w+c3.w;
            }
            #pragma unroll
            for (int dd=0;dd<16;++dd){
                int d = lane*16 + dd;
                const float* w0p = fcW + (size_t)d*NOUT;
                const float* w1p = fcW + (size_t)(d+HH)*NOUT;
                float hv=q[dd], cvv=cv[dd];
                #pragma unroll
                for (int o=0;o<NOUT;o++) acc[o] = fmaf(hv, w0p[o], fmaf(cvv, w1p[o], acc[o]));
            }
            #pragma unroll
            for (int o=0;o<NOUT;o++){
                #pragma unroll
                for (int m=1;m<64;m<<=1) acc[o] += __shfl_xor(acc[o], m);
            }
            float vout = 0.f;
            #pragma unroll
            for (int o=0;o<NOUT;o++) if (lane == o) vout = acc[o] + fcb[o];
            if (lane < NOUT) out[((size_t)b*TT + 99)*NOUT + lane] = vout;
        }
    } else {
        for (int i=0;i<TT;++i) gridbar(bar + (size_t)i*256, wg & 15, 256);
    }
}

extern "C" void kernel_launch(void* const* d_in, const int* in_sizes, int n_in,
                              void* d_out, int out_size, void* d_ws, size_t ws_size,
                              hipStream_t stream){
    (void)in_sizes; (void)n_in; (void)out_size; (void)ws_size;
    const float* x     = (const float*)d_in[0];
    const float* encW  = (const float*)d_in[1];
    const float* encU  = (const float*)d_in[2];
    const float* encb  = (const float*)d_in[3];
    const float* scale = (const float*)d_in[4];
    const float* emb   = (const float*)d_in[5];
    const float* decW  = (const float*)d_in[6];
    const float* decU  = (const float*)d_in[7];
    const float* decb  = (const float*)d_in[8];
    const float* fcW   = (const float*)d_in[9];
    const float* fcb   = (const float*)d_in[10];
    float* out = (float*)d_out;
    float* ws  = (float*)d_ws;

    // ~132.2 MB total (round-4/8/10/11-proven footprint)
    float* MXT   = ws;                        // 19,660,800 (encoder phase only)
    float* hdT   = MXT;                       // dec overlay: 2*65,536 ping-pong [k][b]
    float* hdl   = MXT + 131072;              // dec overlay: 2*65,536 ping-pong [b][k]
    float* encUt = MXT   + 19660800;          // 3,145,728
    float* decUt = encUt + 3145728;           // 3,145,728
    float* hpe   = decUt + 3145728;           // 6,553,600
    float* Edec  = hpe   + 6553600;           // 86,016
    float* hT    = Edec  + 86016;             // 2*65,536 ping-pong [k][b] (encoder)
    int*   ib    = (int*)(hT + 131072);
    int*   bar_enc = ib;                      // 100*256
    int*   bar_dec = ib + 25600;              // 100*256
    int*   flagidx = ib + 51200;              // 100*128
    int*   idx_t   = ib + 64000;              // 100*64   (total 70,400 ints)

    const float* encb1 = encb + H3;
    const float* decb1 = decb + H3;

    k_init<<<276,256,0,stream>>>(ib, 70400);
    k_transpose<<<dim3(96,32,2),256,0,stream>>>(encU, decU, encUt, decUt);
    k_edec<<<336,256,0,stream>>>(emb, decW, decb, Edec);
    k_mxgemm<<<dim3(48,100),256,0,stream>>>(x, encW, encb, MXT);
    k_enc<<<256,256,0,stream>>>(MXT, encUt, encb1, hpe, hT, bar_enc);
    k_dec<<<256,512,0,stream>>>(hpe, decUt, decb1, Edec, scale, fcW, fcb,
                                hdT, hdl, out, idx_t, bar_dec, flagidx);
}

// Round 15
// 9471.684 us; speedup vs baseline: 1.9005x; 1.0630x over previous
//
#include <hip/hip_runtime.h>
#include <hip/hip_fp16.h>

#define TT 100
#define HH 1024
#define H3 3072
#define NOUT 28

#define AGENT __HIP_MEMORY_SCOPE_AGENT
#define WGRP  __HIP_MEMORY_SCOPE_WORKGROUP
#define SPIN_CAP (1u<<20)

typedef float f32x4 __attribute__((ext_vector_type(4)));
typedef unsigned int u32x4 __attribute__((ext_vector_type(4)));

__device__ __forceinline__ float frcp_(float x){ return __builtin_amdgcn_rcpf(x); }
__device__ __forceinline__ float fsig_(float x){ return frcp_(1.0f + __expf(-x)); }
__device__ __forceinline__ float ftanh_(float x){ return 1.0f - 2.0f*frcp_(__expf(2.0f*x) + 1.0f); }
__device__ __forceinline__ void wait_vm(){ asm volatile("s_waitcnt vmcnt(0)" ::: "memory"); }

__device__ __forceinline__ float2 h2f(unsigned w){
    __half2 h = *reinterpret_cast<__half2*>(&w);
    return __half22float2(h);
}

// device-coherent 16B load: bypass L1+L2, read at the coherence point
__device__ __forceinline__ float4 ld_dev16(const float* p){
    float4 v;
    asm volatile("global_load_dwordx4 %0, %1, off sc0 sc1" : "=v"(v) : "v"(p) : "memory");
    return v;
}
// device-coherent 4B load (coalesces across a wave)
__device__ __forceinline__ int ld_dev4i(const int* p){
    int v;
    asm volatile("global_load_dword %0, %1, off sc0 sc1" : "=v"(v) : "v"(p) : "memory");
    return v;
}
// device-coherent stores: write-through to coherence point
__device__ __forceinline__ void st_dev4(float* p, float v){
    asm volatile("global_store_dword %0, %1, off sc0 sc1" :: "v"(p), "v"(v) : "memory");
}
__device__ __forceinline__ void st_dev16(float* p, f32x4 v){
    asm volatile("global_store_dwordx4 %0, %1, off sc0 sc1" :: "v"(p), "v"(v) : "memory");
}
__device__ __forceinline__ unsigned aload4(const int* p){
    return (unsigned)__hip_atomic_load(p, __ATOMIC_RELAXED, AGENT);
}

// grid barrier: 16 padded sub-counters per slot (slot stride = 256 ints), relaxed only.
__device__ __forceinline__ void gridbar(int* slot, int sub, int target){
    __syncthreads();
    if (threadIdx.x == 0){
        __hip_atomic_fetch_add(slot + sub*16, 1, __ATOMIC_RELAXED, AGENT);
        unsigned gy = 0; int s;
        do {
            s = 0;
            #pragma unroll
            for (int c=0;c<16;c++) s += __hip_atomic_load(slot + c*16, __ATOMIC_RELAXED, AGENT);
            if (s < target){ if (++gy > SPIN_CAP) break; __builtin_amdgcn_s_sleep(4); }
        } while (s < target);
    }
    __syncthreads();
}

// barrier among the 4 matmul waves only (LDS counter, monotonic target), capped
__device__ __forceinline__ void wbar4(int* c, int tgt){
    asm volatile("s_waitcnt lgkmcnt(0)" ::: "memory");
    if ((threadIdx.x & 63) == 0) __hip_atomic_fetch_add(c, 1, __ATOMIC_RELAXED, WGRP);
    unsigned gy = 0;
    while (__hip_atomic_load(c, __ATOMIC_RELAXED, WGRP) < tgt){ if (++gy > SPIN_CAP) break; }
    asm volatile("" ::: "memory");
}

// ---------------- init: zero control ints ----------------
__global__ void k_init(int* ib, int n){
    int g = blockIdx.x*256 + threadIdx.x;
    if (g < n) ib[g] = 0;
}

// ---------------- transpose U [1024][3072] -> Ut [3072][1024] ----------------
__global__ __launch_bounds__(256) void k_transpose(const float* __restrict__ U0,
                                                   const float* __restrict__ U1,
                                                   float* __restrict__ T0,
                                                   float* __restrict__ T1){
    const float* U = blockIdx.z ? U1 : U0;
    float*       T = blockIdx.z ? T1 : T0;
    __shared__ float tile[32][33];
    int tx = threadIdx.x & 31, ty = threadIdx.x >> 5;
    int j0 = blockIdx.x*32, k0 = blockIdx.y*32;
    #pragma unroll
    for (int q=0;q<4;q++){
        int kr = ty + q*8;
        tile[kr][tx] = U[(size_t)(k0+kr)*H3 + j0 + tx];
    }
    __syncthreads();
    #pragma unroll
    for (int q=0;q<4;q++){
        int jr = ty + q*8;
        T[(size_t)(j0+jr)*HH + k0 + tx] = tile[tx][jr];
    }
}

// ---------------- Edec[28][3072] = emb @ decW + decb[0] ----------------
__global__ __launch_bounds__(256) void k_edec(const float* __restrict__ emb,
                                              const float* __restrict__ W,
                                              const float* __restrict__ b0,
                                              float* __restrict__ E){
    int gid = blockIdx.x*256 + threadIdx.x;   // 28*3072 = 86016
    int v = gid / H3, j = gid - v*H3;
    float acc = b0[j];
    const float* er = emb + (size_t)v*HH;
    #pragma unroll 4
    for (int k=0;k<HH;k++) acc = fmaf(er[k], W[(size_t)k*H3 + j], acc);
    E[gid] = acc;
}

// ---------------- MXT[t][col][b] = (x2d @ encW + encb[0]) transposed ----------------
__global__ __launch_bounds__(256) void k_mxgemm(const float* __restrict__ A,
                                                const float* __restrict__ W,
                                                const float* __restrict__ b0,
                                                float* __restrict__ MXT){
    __shared__ float aT[32*68];
    __shared__ float bL[32*68];
    int tid = threadIdx.x;
    int row0 = blockIdx.y*64, col0 = blockIdx.x*64;
    int arow = tid>>2, acs = (tid&3)*4;
    int bk   = tid>>3, bcs = (tid&7)*4;
    int ty = tid>>4, tx = tid&15;
    float acc[4][4] = {};
    for (int kk=0; kk<HH; kk+=32){
        #pragma unroll
        for (int i=0;i<2;i++){
            int c = acs + i*16;
            float4 v = *(const float4*)(A + (size_t)(row0+arow)*HH + kk + c);
            aT[(c+0)*68 + arow] = v.x; aT[(c+1)*68 + arow] = v.y;
            aT[(c+2)*68 + arow] = v.z; aT[(c+3)*68 + arow] = v.w;
        }
        #pragma unroll
        for (int i=0;i<2;i++){
            int c = bcs + i*32;
            float4 v = *(const float4*)(W + (size_t)(kk+bk)*H3 + col0 + c);
            *(float4*)(bL + bk*68 + c) = v;
        }
        __syncthreads();
        #pragma unroll
        for (int k=0;k<32;k++){
            float4 a4 = *(const float4*)(aT + k*68 + ty*4);
            float4 b4 = *(const float4*)(bL + k*68 + tx*4);
            acc[0][0]=fmaf(a4.x,b4.x,acc[0][0]); acc[0][1]=fmaf(a4.x,b4.y,acc[0][1]);
            acc[0][2]=fmaf(a4.x,b4.z,acc[0][2]); acc[0][3]=fmaf(a4.x,b4.w,acc[0][3]);
            acc[1][0]=fmaf(a4.y,b4.x,acc[1][0]); acc[1][1]=fmaf(a4.y,b4.y,acc[1][1]);
            acc[1][2]=fmaf(a4.y,b4.z,acc[1][2]); acc[1][3]=fmaf(a4.y,b4.w,acc[1][3]);
            acc[2][0]=fmaf(a4.z,b4.x,acc[2][0]); acc[2][1]=fmaf(a4.z,b4.y,acc[2][1]);
            acc[2][2]=fmaf(a4.z,b4.z,acc[2][2]); acc[2][3]=fmaf(a4.z,b4.w,acc[2][3]);
            acc[3][0]=fmaf(a4.w,b4.x,acc[3][0]); acc[3][1]=fmaf(a4.w,b4.y,acc[3][1]);
            acc[3][2]=fmaf(a4.w,b4.z,acc[3][2]); acc[3][3]=fmaf(a4.w,b4.w,acc[3][3]);
        }
        __syncthreads();
    }
    float4 bb = *(const float4*)(b0 + col0 + tx*4);
    #pragma unroll
    for (int i=0;i<4;i++){
        int r = row0 + ty*4 + i;
        int bq = r / 100; int tq = r - bq*100;
        float v0 = acc[i][0] + bb.x, v1 = acc[i][1] + bb.y;
        float v2 = acc[i][2] + bb.z, v3 = acc[i][3] + bb.w;
        float* dst = MXT + ((size_t)tq*H3 + col0 + tx*4)*64 + bq;
        dst[0]   = v0; dst[64]  = v1; dst[128] = v2; dst[192] = v3;
    }
}

// ---------------- persistent encoder: 256 WGs x 256 thr ----------------
__global__ __launch_bounds__(256) void k_enc(const float* __restrict__ MXT,
                                             const float* __restrict__ Ut,
                                             const float* __restrict__ b1,
                                             __half* __restrict__ hpe,
                                             float* __restrict__ hT,
                                             int* __restrict__ bar){
    __shared__ float hs[2][16384];
    int tid = threadIdx.x, lane = tid & 63;
    int wg = blockIdx.x;
    int sub = wg & 15;
    int cu = __builtin_amdgcn_readfirstlane(wg*4 + (tid>>6));
    const float* Uz = Ut + (size_t)cu*HH;
    const float* Ur = Uz + (size_t)HH*HH;
    const float* Uh = Ur + (size_t)HH*HH;
    float bz = b1[cu], br = b1[cu+HH], bh = b1[cu+2*HH];
    for (int t=0; t<TT; ++t){
        int cur = t & 1;
        const float* mx = MXT + (size_t)t*H3*64;
        float xz = mx[(size_t)cu*64 + lane];
        float xr = mx[(size_t)(cu+HH)*64 + lane];
        float xh = mx[(size_t)(cu+2*HH)*64 + lane];
        float az=0.f, ar=0.f, ah=0.f, hp=0.f;
        if (t > 0){
            const float* gq = hT + (size_t)cur*65536;
            float4 sv[16];
            #pragma unroll
            for (int s=0;s<16;s++) sv[s] = ld_dev16(gq + 4*(size_t)(s*256 + tid));
            wait_vm();
            #pragma unroll
            for (int s=0;s<16;s++) ((float4*)hs[0])[s*256 + tid] = sv[s];
            __syncthreads();
            for (int q=0;q<4;++q){
                if (q<3){
                    #pragma unroll
                    for (int s=0;s<16;s++) sv[s] = ld_dev16(gq + (size_t)(q+1)*16384 + 4*(size_t)(s*256 + tid));
                }
                const float* hb = hs[q&1];
                const float* Uzq = Uz + q*256;
                const float* Urq = Ur + q*256;
                const float* Uhq = Uh + q*256;
                #pragma unroll 8
                for (int k=0;k<256;++k){
                    float h = hb[k*64 + lane];
                    az = fmaf(h, Uzq[k], az);
                    ar = fmaf(h, Urq[k], ar);
                    ah = fmaf(h, Uhq[k], ah);
                }
                if ((cu>>8) == q) hp = hb[(cu&255)*64 + lane];
                if (q<3){
                    wait_vm();
                    #pragma unroll
                    for (int s=0;s<16;s++) ((float4*)hs[(q+1)&1])[s*256 + tid] = sv[s];
                }
                __syncthreads();
            }
        }
        float z  = fsig_(xz + az + bz);
        float r  = fsig_(xr + ar + br);
        float hh = ftanh_(xh + r*(ah + bh));
        float hnew = z*hp + (1.f - z)*hh;
        st_dev4(hT + (size_t)(cur^1)*65536 + cu*64 + lane, hnew);   // coalesced publish
        hpe[((size_t)lane*TT + t)*HH + cu] = __float2half_rn(hnew); // fp16 attention stream
        gridbar(bar + (size_t)t*256, sub, 256);
    }
}

// ---------------- persistent decoder: 256 WGs x 512 thr ----------------
// waves 0-3: GRU matmul (unit = wg*4+wave, lane = batch); waves 4-7 on wg<64: attention team b=wg
__global__ __launch_bounds__(512) void k_dec(const __half* __restrict__ hpe,
                                             const float* __restrict__ Ut,
                                             const float* __restrict__ b1,
                                             const float* __restrict__ Edec,
                                             const float* __restrict__ scale,
                                             const float* __restrict__ fcW,
                                             const float* __restrict__ fcb,
                                             float* __restrict__ hdT,
                                             float* __restrict__ hdl,
                                             float* __restrict__ out,
                                             int* __restrict__ idx_t,
                                             int* __restrict__ bar,
                                             int* __restrict__ flagidx){
    __shared__ float hs[2][16384];
    __shared__ float ctxs[4][1024];
    __shared__ float edl[4][3][28];
    __shared__ float trs[256];
    __shared__ float m_s[4], S_s[4];
    __shared__ int c_a, c_fc, go, cstg;
    int tid = threadIdx.x, wg = blockIdx.x;
    if (tid == 0){ c_a=0; c_fc=0; go=0; cstg=0; }
    __syncthreads();

    if (tid < 256){
        // ============ matmul role ============
        int lane = tid & 63;
        int sub = wg & 15;
        int wv = tid >> 6;
        int cu = __builtin_amdgcn_readfirstlane(wg*4 + wv);
        const float* Uz = Ut + (size_t)cu*HH;
        const float* Ur = Uz + (size_t)HH*HH;
        const float* Uh = Ur + (size_t)HH*HH;
        float bz = b1[cu], br = b1[cu+HH], bh = b1[cu+2*HH];
        for (int tq = lane; tq < 84; tq += 64){
            int g = tq / 28, v = tq - g*28;
            edl[wv][g][v] = Edec[(size_t)v*H3 + cu + g*HH];
        }
        int stgt = 0;
        for (int i=0; i<TT; ++i){
            int cur = i & 1;
            float az=0.f, ar=0.f, ah=0.f, hp=0.f;
            if (i > 0){
                const float* gq = hdT + (size_t)cur*65536;
                float4 sv[16];
                #pragma unroll
                for (int s=0;s<16;s++) sv[s] = ld_dev16(gq + 4*(size_t)(s*256 + tid));
                wait_vm();
                #pragma unroll
                for (int s=0;s<16;s++) ((float4*)hs[0])[s*256 + tid] = sv[s];
                wbar4(&cstg, stgt += 4);
                for (int q=0;q<4;++q){
                    if (q<3){
                        #pragma unroll
                        for (int s=0;s<16;s++) sv[s] = ld_dev16(gq + (size_t)(q+1)*16384 + 4*(size_t)(s*256 + tid));
                    }
                    const float* hb = hs[q&1];
                    const float* Uzq = Uz + q*256;
                    const float* Urq = Ur + q*256;
                    const float* Uhq = Uh + q*256;
                    #pragma unroll 8
                    for (int k=0;k<256;++k){
                        float h = hb[k*64 + lane];
                        az = fmaf(h, Uzq[k], az);
                        ar = fmaf(h, Urq[k], ar);
                        ah = fmaf(h, Uhq[k], ah);
                    }
                    if ((cu>>8) == q) hp = hb[(cu&255)*64 + lane];
                    if (q<3){
                        wait_vm();
                        #pragma unroll
                        for (int s=0;s<16;s++) ((float4*)hs[(q+1)&1])[s*256 + tid] = sv[s];
                    }
                    wbar4(&cstg, stgt += 4);
                }
            }
            // wait for idx(i): single poller + LDS broadcast
            if (tid == 0){
                unsigned gy = 0; int s;
                do {
                    s = 0;
                    #pragma unroll
                    for (int c=0;c<8;c++) s += __hip_atomic_load(flagidx + (size_t)i*128 + c*16, __ATOMIC_RELAXED, AGENT);
                    if (s < 64){ if (++gy > SPIN_CAP) break; __builtin_amdgcn_s_sleep(4); }
                } while (s < 64);
                __hip_atomic_store(&go, i+1, __ATOMIC_RELAXED, WGRP);
            }
            { unsigned gy=0; while (__hip_atomic_load(&go, __ATOMIC_RELAXED, WGRP) < i+1){ if (++gy > SPIN_CAP) break; } }
            asm volatile("" ::: "memory");
            int mi_raw = ld_dev4i(idx_t + (size_t)i*64 + lane);
            wait_vm();
            unsigned mi = (unsigned)mi_raw;
            if (mi > 27u) mi = 0;
            float xz = edl[wv][0][mi];
            float xr = edl[wv][1][mi];
            float xh = edl[wv][2][mi];
            float z  = fsig_(xz + az + bz);
            float r  = fsig_(xr + ar + br);
            float hh = ftanh_(xh + r*(ah + bh));
            float hnew = z*hp + (1.f - z)*hh;
            st_dev4(hdT + (size_t)(cur^1)*65536 + cu*64 + lane, hnew);   // coalesced
            // hdl publish: LDS transpose -> wave 0 stores 64 x dwordx4 (coalesced lines)
            trs[lane*4 + wv] = hnew;
            wbar4(&cstg, stgt += 4);
            if (wv == 0){
                f32x4 h4 = *(const f32x4*)(trs + lane*4);
                st_dev16(hdl + (size_t)(cur^1)*65536 + (size_t)lane*HH + wg*4, h4);
            }
            gridbar(bar + (size_t)i*256, sub, 256);
        }
    } else if (wg < 64){
        // ============ attention team for batch b = wg ============
        int t2 = tid - 256;
        int w = t2 >> 6, lane = t2 & 63, b = wg;
        float sc[16];
        #pragma unroll
        for (int s4=0;s4<4;s4++){
            float4 v = *(const float4*)(scale + lane*16 + s4*4);
            sc[s4*4+0]=v.x; sc[s4*4+1]=v.y; sc[s4*4+2]=v.z; sc[s4*4+3]=v.w;
        }
        int j0 = w*25;
        const __half* hpb = hpe + ((size_t)b*TT + j0)*HH + lane*16;
        for (int i=0; i<TT; ++i){
            float q[16];
            if (i == 0){
                #pragma unroll
                for (int d=0;d<16;d++) q[d]=0.f;
            } else {
                const float* hq = hdl + (size_t)(i&1)*65536 + (size_t)b*HH + lane*16;
                float4 q0 = ld_dev16(hq), q1 = ld_dev16(hq+4), q2 = ld_dev16(hq+8), q3 = ld_dev16(hq+12);
                wait_vm();
                q[0]=q0.x;q[1]=q0.y;q[2]=q0.z;q[3]=q0.w;
                q[4]=q1.x;q[5]=q1.y;q[6]=q1.z;q[7]=q1.w;
                q[8]=q2.x;q[9]=q2.y;q[10]=q2.z;q[11]=q2.w;
                q[12]=q3.x;q[13]=q3.y;q[14]=q3.z;q[15]=q3.w;
            }
            if (w == 0){
                if (i > 0){
                    float acc[NOUT];
                    #pragma unroll
                    for (int o=0;o<NOUT;o++) acc[o]=0.f;
                    float cv[16];
                    #pragma unroll
                    for (int s4=0;s4<4;s4++){
                        float4 c0 = ((const float4*)ctxs[0])[lane*4+s4];
                        float4 c1 = ((const float4*)ctxs[1])[lane*4+s4];
                        float4 c2 = ((const float4*)ctxs[2])[lane*4+s4];
                        float4 c3 = ((const float4*)ctxs[3])[lane*4+s4];
                        cv[s4*4+0]=c0.x+c1.x+c2.x+c3.x;
                        cv[s4*4+1]=c0.y+c1.y+c2.y+c3.y;
                        cv[s4*4+2]=c0.z+c1.z+c2.z+c3.z;
                        cv[s4*4+3]=c0.w+c1.w+c2.w+c3.w;
                    }
                    #pragma unroll
                    for (int dd=0;dd<16;++dd){
                        int d = lane*16 + dd;
                        const float* w0p = fcW + (size_t)d*NOUT;
                        const float* w1p = fcW + (size_t)(d+HH)*NOUT;
                        float hv=q[dd], cvv=cv[dd];
                        #pragma unroll
                        for (int o=0;o<NOUT;o++) acc[o] = fmaf(hv, w0p[o], fmaf(cvv, w1p[o], acc[o]));
                    }
                    #pragma unroll
                    for (int o=0;o<NOUT;o++){
                        #pragma unroll
                        for (int m=1;m<64;m<<=1) acc[o] += __shfl_xor(acc[o], m);
                    }
                    float bv=-3.0e38f; int bi=0;
                    #pragma unroll
                    for (int o=0;o<NOUT;o++){
                        float p = acc[o] + fcb[o];
                        acc[o] = p;
                        if (p > bv){ bv = p; bi = o; }
                    }
                    float vout = 0.f;
                    #pragma unroll
                    for (int o=0;o<NOUT;o++) if (lane == o) vout = acc[o];
                    if (lane < NOUT) out[((size_t)b*TT + (i-1))*NOUT + lane] = vout;
                    if (lane == 0){
                        __hip_atomic_store(idx_t + (size_t)i*64 + b, bi, __ATOMIC_RELAXED, AGENT);
                        asm volatile("s_waitcnt vmcnt(0)" ::: "memory");
                    }
                }
                if (lane == 0){
                    __hip_atomic_fetch_add(flagidx + (size_t)i*128 + (b&7)*16, 1, __ATOMIC_RELAXED, AGENT);
                    __hip_atomic_fetch_add(&c_fc, 1, __ATOMIC_RELAXED, WGRP);
                }
            }
            // ---- online-softmax, hpe (fp16) read once, next-row prefetch ----
            float m = -3.0e38f, S = 0.f;
            float a[16];
            #pragma unroll
            for (int d=0;d<16;d++) a[d]=0.f;
            u32x4 n0 = *(const u32x4*)(hpb);
            u32x4 n1 = *(const u32x4*)(hpb + 8);
            for (int jj=0;jj<25;jj++){
                u32x4 v0=n0, v1=n1;
                if (jj < 24){
                    const __half* hpn = hpb + (size_t)(jj+1)*HH;
                    n0 = *(const u32x4*)(hpn);
                    n1 = *(const u32x4*)(hpn + 8);
                }
                float va[16];
                float2 f;
                f=h2f(v0.x); va[0]=f.x; va[1]=f.y;  f=h2f(v0.y); va[2]=f.x; va[3]=f.y;
                f=h2f(v0.z); va[4]=f.x; va[5]=f.y;  f=h2f(v0.w); va[6]=f.x; va[7]=f.y;
                f=h2f(v1.x); va[8]=f.x; va[9]=f.y;  f=h2f(v1.y); va[10]=f.x; va[11]=f.y;
                f=h2f(v1.z); va[12]=f.x; va[13]=f.y; f=h2f(v1.w); va[14]=f.x; va[15]=f.y;
                float s = 0.f;
                #pragma unroll
                for (int d=0;d<16;d++) s += sc[d]*ftanh_(q[d] + va[d]);
                #pragma unroll
                for (int mm=1;mm<64;mm<<=1) s += __shfl_xor(s, mm);
                float mn = fmaxf(m, s);
                float fold = __expf(m - mn);
                float e = __expf(s - mn);
                S = S*fold + e;
                #pragma unroll
                for (int d=0;d<16;d++) a[d] = a[d]*fold + e*va[d];
                m = mn;
            }
            if (lane == 0){ m_s[w] = m; S_s[w] = S; }
            asm volatile("s_waitcnt lgkmcnt(0)" ::: "memory");
            if (lane == 0) __hip_atomic_fetch_add(&c_a, 1, __ATOMIC_RELAXED, WGRP);
            { unsigned gy=0; while (__hip_atomic_load(&c_a, __ATOMIC_RELAXED, WGRP) < 4*(i+1)){ if (++gy > SPIN_CAP) break; } }
            asm volatile("" ::: "memory");
            float M = fmaxf(fmaxf(m_s[0],m_s[1]), fmaxf(m_s[2],m_s[3]));
            float St = S_s[0]*__expf(m_s[0]-M) + S_s[1]*__expf(m_s[1]-M)
                     + S_s[2]*__expf(m_s[2]-M) + S_s[3]*__expf(m_s[3]-M);
            float g = __expf(m - M) * frcp_(St);
            // wait until fc consumed ctxs of step i-1
            { unsigned gy=0; while (__hip_atomic_load(&c_fc, __ATOMIC_RELAXED, WGRP) < i+1){ if (++gy > SPIN_CAP) break; } }
            asm volatile("" ::: "memory");
            #pragma unroll
            for (int s4=0;s4<4;s4++){
                float4 o4;
                o4.x=a[s4*4+0]*g; o4.y=a[s4*4+1]*g;
                o4.z=a[s4*4+2]*g; o4.w=a[s4*4+3]*g;
                ((float4*)ctxs[w])[lane*4 + s4] = o4;
            }
            gridbar(bar + (size_t)i*256, wg & 15, 256);
        }
        // epilogue: p(99) = [hd(100), ctx(99)] @ fc ; hd(100) is in hdl slot 0
        if (w == 0){
            const float* hq = hdl + (size_t)b*HH + lane*16;
            float4 q0 = ld_dev16(hq), q1 = ld_dev16(hq+4), q2 = ld_dev16(hq+8), q3 = ld_dev16(hq+12);
            wait_vm();
            float q[16];
            q[0]=q0.x;q[1]=q0.y;q[2]=q0.z;q[3]=q0.w;
            q[4]=q1.x;q[5]=q1.y;q[6]=q1.z;q[7]=q1.w;
            q[8]=q2.x;q[9]=q2.y;q[10]=q2.z;q[11]=q2.w;
            q[12]=q3.x;q[13]=q3.y;q[14]=q3.z;q[15]=q3.w;
            float acc[NOUT];
            #pragma unroll
            for (int o=0;o<NOUT;o++) acc[o]=0.f;
            float cv[16];
            #pragma unroll
            for (int s4=0;s4<4;s4++){
                float4 c0 = ((const float4*)ctxs[0])[lane*4+s4];
                float4 c1 = ((const float4*)ctxs[1])[lane*4+s4];
                float4 c2 = ((const float4*)ctxs[2])[lane*4+s4];
                float4 c3 = ((const float4*)ctxs[3])[lane*4+s4];
                cv[s4*4+0]=c0.x+c1.x+c2.x+c3.x;
                cv[s4*4+1]=c0.y+c1.y+c2.y+c3.y;
                cv[s4*4+2]=c0.z+c1.z+c2.z+c3.z;
                cv[s4*4+3]=c0.w+c1.w+c2.w+c3.w;
            }
            #pragma unroll
            for (int dd=0;dd<16;++dd){
                int d = lane*16 + dd;
                const float* w0p = fcW + (size_t)d*NOUT;
                const float* w1p = fcW + (size_t)(d+HH)*NOUT;
                float hv=q[dd], cvv=cv[dd];
                #pragma unroll
                for (int o=0;o<NOUT;o++) acc[o] = fmaf(hv, w0p[o], fmaf(cvv, w1p[o], acc[o]));
            }
            #pragma unroll
            for (int o=0;o<NOUT;o++){
                #pragma unroll
                for (int m=1;m<64;m<<=1) acc[o] += __shfl_xor(acc[o], m);
            }
            float vout = 0.f;
            #pragma unroll
            for (int o=0;o<NOUT;o++) if (lane == o) vout = acc[o] + fcb[o];
            if (lane < NOUT) out[((size_t)b*TT + 99)*NOUT + lane] = vout;
        }
    } else {
        for (int i=0;i<TT;++i) gridbar(bar + (size_t)i*256, wg & 15, 256);
    }
}

extern "C" void kernel_launch(void* const* d_in, const int* in_sizes, int n_in,
                              void* d_out, int out_size, void* d_ws, size_t ws_size,
                              hipStream_t stream){
    (void)in_sizes; (void)n_in; (void)out_size; (void)ws_size;
    const float* x     = (const float*)d_in[0];
    const float* encW  = (const float*)d_in[1];
    const float* encU  = (const float*)d_in[2];
    const float* encb  = (const float*)d_in[3];
    const float* scale = (const float*)d_in[4];
    const float* emb   = (const float*)d_in[5];
    const float* decW  = (const float*)d_in[6];
    const float* decU  = (const float*)d_in[7];
    const float* decb  = (const float*)d_in[8];
    const float* fcW   = (const float*)d_in[9];
    const float* fcb   = (const float*)d_in[10];
    float* out = (float*)d_out;
    float* ws  = (float*)d_ws;

    // same float-offset map as rounds 8-13 (hpe used as half within its region)
    float* MXT   = ws;                        // 19,660,800 (encoder phase only)
    float* hdT   = MXT;                       // dec overlay: 2*65,536 ping-pong [k][b] (fp32)
    float* hdl   = MXT + 131072;              // dec overlay: 2*65,536 ping-pong [b][k] (fp32)
    float* encUt = MXT   + 19660800;          // 3,145,728
    float* decUt = encUt + 3145728;           // 3,145,728
    float* hpeF  = decUt + 3145728;           // region 6,553,600 floats; used as 6,553,600 halves
    __half* hpe  = (__half*)hpeF;
    float* Edec  = hpeF  + 6553600;           // 86,016
    float* hT    = Edec  + 86016;             // 2*65,536 ping-pong [k][b] (encoder, fp32)
    int*   ib    = (int*)(hT + 131072);
    int*   bar_enc = ib;                      // 100*256
    int*   bar_dec = ib + 25600;              // 100*256
    int*   flagidx = ib + 51200;              // 100*128
    int*   idx_t   = ib + 64000;              // 100*64   (total 70,400 ints)

    const float* encb1 = encb + H3;
    const float* decb1 = decb + H3;

    k_init<<<276,256,0,stream>>>(ib, 70400);
    k_transpose<<<dim3(96,32,2),256,0,stream>>>(encU, decU, encUt, decUt);
    k_edec<<<336,256,0,stream>>>(emb, decW, decb, Edec);
    k_mxgemm<<<dim3(48,100),256,0,stream>>>(x, encW, encb, MXT);
    k_enc<<<256,256,0,stream>>>(MXT, encUt, encb1, hpe, hT, bar_enc);
    k_dec<<<256,512,0,stream>>>(hpe, decUt, decb1, Edec, scale, fcW, fcb,
                                hdT, hdl, out, idx_t, bar_dec, flagidx);
}

// Round 18
// 9342.941 us; speedup vs baseline: 1.9266x; 1.0138x over previous
//
#include <hip/hip_runtime.h>
#include <hip/hip_fp16.h>

#define TT 100
#define HH 1024
#define H3 3072
#define NOUT 28

#define AGENT __HIP_MEMORY_SCOPE_AGENT
#define WGRP  __HIP_MEMORY_SCOPE_WORKGROUP
#define SPIN_CAP (1u<<20)

typedef float f32x4 __attribute__((ext_vector_type(4)));
typedef unsigned int u32x4 __attribute__((ext_vector_type(4)));

__device__ __forceinline__ float frcp_(float x){ return __builtin_amdgcn_rcpf(x); }
__device__ __forceinline__ float fsig_(float x){ return frcp_(1.0f + __expf(-x)); }
__device__ __forceinline__ float ftanh_(float x){ return 1.0f - 2.0f*frcp_(__expf(2.0f*x) + 1.0f); }
__device__ __forceinline__ void wait_vm(){ asm volatile("s_waitcnt vmcnt(0)" ::: "memory"); }

__device__ __forceinline__ float2 h2f(unsigned w){
    __half2 h = *reinterpret_cast<__half2*>(&w);
    return __half22float2(h);
}

// device-coherent primitives (bypass L1+L2, served at coherence point) — fp32 only (proven)
__device__ __forceinline__ float4 ld_dev16(const float* p){
    float4 v;
    asm volatile("global_load_dwordx4 %0, %1, off sc0 sc1" : "=v"(v) : "v"(p) : "memory");
    return v;
}
__device__ __forceinline__ int ld_dev4i(const int* p){
    int v;
    asm volatile("global_load_dword %0, %1, off sc0 sc1" : "=v"(v) : "v"(p) : "memory");
    return v;
}
__device__ __forceinline__ void st_dev4(float* p, float v){
    asm volatile("global_store_dword %0, %1, off sc0 sc1" :: "v"(p), "v"(v) : "memory");
}
__device__ __forceinline__ void st_dev16(float* p, f32x4 v){
    asm volatile("global_store_dwordx4 %0, %1, off sc0 sc1" :: "v"(p), "v"(v) : "memory");
}
__device__ __forceinline__ unsigned aload4(const int* p){
    return (unsigned)__hip_atomic_load(p, __ATOMIC_RELAXED, AGENT);
}

// grid barrier: 16 padded sub-counters per slot (slot stride = 256 ints), relaxed only.
__device__ __forceinline__ void gridbar(int* slot, int sub, int target){
    __syncthreads();
    if (threadIdx.x == 0){
        __hip_atomic_fetch_add(slot + sub*16, 1, __ATOMIC_RELAXED, AGENT);
        unsigned gy = 0; int s;
        do {
            s = 0;
            #pragma unroll
            for (int c=0;c<16;c++) s += __hip_atomic_load(slot + c*16, __ATOMIC_RELAXED, AGENT);
            if (s < target){ if (++gy > SPIN_CAP) break; __builtin_amdgcn_s_sleep(4); }
        } while (s < target);
    }
    __syncthreads();
}

// barrier among the 4 matmul waves only (LDS counter, monotonic target), capped
__device__ __forceinline__ void wbar4(int* c, int tgt){
    asm volatile("s_waitcnt lgkmcnt(0)" ::: "memory");
    if ((threadIdx.x & 63) == 0) __hip_atomic_fetch_add(c, 1, __ATOMIC_RELAXED, WGRP);
    unsigned gy = 0;
    while (__hip_atomic_load(c, __ATOMIC_RELAXED, WGRP) < tgt){ if (++gy > SPIN_CAP) break; }
    asm volatile("" ::: "memory");
}

// ---------------- init: zero control ints ----------------
__global__ void k_init(int* ib, int n){
    int g = blockIdx.x*256 + threadIdx.x;
    if (g < n) ib[g] = 0;
}

// ---------------- transpose U [1024][3072] -> Ut [3072][1024] ----------------
__global__ __launch_bounds__(256) void k_transpose(const float* __restrict__ U0,
                                                   const float* __restrict__ U1,
                                                   float* __restrict__ T0,
                                                   float* __restrict__ T1){
    const float* U = blockIdx.z ? U1 : U0;
    float*       T = blockIdx.z ? T1 : T0;
    __shared__ float tile[32][33];
    int tx = threadIdx.x & 31, ty = threadIdx.x >> 5;
    int j0 = blockIdx.x*32, k0 = blockIdx.y*32;
    #pragma unroll
    for (int q=0;q<4;q++){
        int kr = ty + q*8;
        tile[kr][tx] = U[(size_t)(k0+kr)*H3 + j0 + tx];
    }
    __syncthreads();
    #pragma unroll
    for (int q=0;q<4;q++){
        int jr = ty + q*8;
        T[(size_t)(j0+jr)*HH + k0 + tx] = tile[tx][jr];
    }
}

// ---------------- Edec[28][3072] = emb @ decW + decb[0] ----------------
__global__ __launch_bounds__(256) void k_edec(const float* __restrict__ emb,
                                              const float* __restrict__ W,
                                              const float* __restrict__ b0,
                                              float* __restrict__ E){
    int gid = blockIdx.x*256 + threadIdx.x;   // 28*3072 = 86016
    int v = gid / H3, j = gid - v*H3;
    float acc = b0[j];
    const float* er = emb + (size_t)v*HH;
    #pragma unroll 4
    for (int k=0;k<HH;k++) acc = fmaf(er[k], W[(size_t)k*H3 + j], acc);
    E[gid] = acc;
}

// ---------------- MXT[t][col][b] = (x2d @ encW + encb[0]) transposed ----------------
__global__ __launch_bounds__(256) void k_mxgemm(const float* __restrict__ A,
                                                const float* __restrict__ W,
                                                const float* __restrict__ b0,
                                                float* __restrict__ MXT){
    __shared__ float aT[32*68];
    __shared__ float bL[32*68];
    int tid = threadIdx.x;
    int row0 = blockIdx.y*64, col0 = blockIdx.x*64;
    int arow = tid>>2, acs = (tid&3)*4;
    int bk   = tid>>3, bcs = (tid&7)*4;
    int ty = tid>>4, tx = tid&15;
    float acc[4][4] = {};
    for (int kk=0; kk<HH; kk+=32){
        #pragma unroll
        for (int i=0;i<2;i++){
            int c = acs + i*16;
            float4 v = *(const float4*)(A + (size_t)(row0+arow)*HH + kk + c);
            aT[(c+0)*68 + arow] = v.x; aT[(c+1)*68 + arow] = v.y;
            aT[(c+2)*68 + arow] = v.z; aT[(c+3)*68 + arow] = v.w;
        }
        #pragma unroll
        for (int i=0;i<2;i++){
            int c = bcs + i*32;
            float4 v = *(const float4*)(W + (size_t)(kk+bk)*H3 + col0 + c);
            *(float4*)(bL + bk*68 + c) = v;
        }
        __syncthreads();
        #pragma unroll
        for (int k=0;k<32;k++){
            float4 a4 = *(const float4*)(aT + k*68 + ty*4);
            float4 b4 = *(const float4*)(bL + k*68 + tx*4);
            acc[0][0]=fmaf(a4.x,b4.x,acc[0][0]); acc[0][1]=fmaf(a4.x,b4.y,acc[0][1]);
            acc[0][2]=fmaf(a4.x,b4.z,acc[0][2]); acc[0][3]=fmaf(a4.x,b4.w,acc[0][3]);
            acc[1][0]=fmaf(a4.y,b4.x,acc[1][0]); acc[1][1]=fmaf(a4.y,b4.y,acc[1][1]);
            acc[1][2]=fmaf(a4.y,b4.z,acc[1][2]); acc[1][3]=fmaf(a4.y,b4.w,acc[1][3]);
            acc[2][0]=fmaf(a4.z,b4.x,acc[2][0]); acc[2][1]=fmaf(a4.z,b4.y,acc[2][1]);
            acc[2][2]=fmaf(a4.z,b4.z,acc[2][2]); acc[2][3]=fmaf(a4.z,b4.w,acc[2][3]);
            acc[3][0]=fmaf(a4.w,b4.x,acc[3][0]); acc[3][1]=fmaf(a4.w,b4.y,acc[3][1]);
            acc[3][2]=fmaf(a4.w,b4.z,acc[3][2]); acc[3][3]=fmaf(a4.w,b4.w,acc[3][3]);
        }
        __syncthreads();
    }
    float4 bb = *(const float4*)(b0 + col0 + tx*4);
    #pragma unroll
    for (int i=0;i<4;i++){
        int r = row0 + ty*4 + i;
        int bq = r / 100; int tq = r - bq*100;
        float v0 = acc[i][0] + bb.x, v1 = acc[i][1] + bb.y;
        float v2 = acc[i][2] + bb.z, v3 = acc[i][3] + bb.w;
        float* dst = MXT + ((size_t)tq*H3 + col0 + tx*4)*64 + bq;
        dst[0]   = v0; dst[64]  = v1; dst[128] = v2; dst[192] = v3;
    }
}

// ---------------- persistent encoder: 128 WGs x 512 thr, 8 waves x 1 unit ----------------
// Same per-wave math as the 256x256 version (bit-identical); half the broadcast consumers.
__global__ __launch_bounds__(512) void k_enc(const float* __restrict__ MXT,
                                             const float* __restrict__ Ut,
                                             const float* __restrict__ b1,
                                             __half* __restrict__ hpe,
                                             float* __restrict__ hT,
                                             int* __restrict__ bar){
    __shared__ float hs[2][16384];
    int tid = threadIdx.x, lane = tid & 63;
    int wg = blockIdx.x;
    int sub = wg & 15;
    int cu = __builtin_amdgcn_readfirstlane(wg*8 + (tid>>6));   // unit 0..1023
    const float* Uz = Ut + (size_t)cu*HH;
    const float* Ur = Uz + (size_t)HH*HH;
    const float* Uh = Ur + (size_t)HH*HH;
    float bz = b1[cu], br = b1[cu+HH], bh = b1[cu+2*HH];
    for (int t=0; t<TT; ++t){
        int cur = t & 1;
        const float* mx = MXT + (size_t)t*H3*64;
        float xz = mx[(size_t)cu*64 + lane];
        float xr = mx[(size_t)(cu+HH)*64 + lane];
        float xh = mx[(size_t)(cu+2*HH)*64 + lane];
        float az=0.f, ar=0.f, ah=0.f, hp=0.f;
        if (t > 0){
            const float* gq = hT + (size_t)cur*65536;
            float4 sv[8];
            #pragma unroll
            for (int s=0;s<8;s++) sv[s] = ld_dev16(gq + 4*(size_t)(s*512 + tid));
            wait_vm();
            #pragma unroll
            for (int s=0;s<8;s++) ((float4*)hs[0])[s*512 + tid] = sv[s];
            __syncthreads();
            for (int q=0;q<4;++q){
                if (q<3){
                    #pragma unroll
                    for (int s=0;s<8;s++) sv[s] = ld_dev16(gq + (size_t)(q+1)*16384 + 4*(size_t)(s*512 + tid));
                }
                const float* hb = hs[q&1];
                const float* Uzq = Uz + q*256;
                const float* Urq = Ur + q*256;
                const float* Uhq = Uh + q*256;
                #pragma unroll 8
                for (int k=0;k<256;++k){
                    float h = hb[k*64 + lane];
                    az = fmaf(h, Uzq[k], az);
                    ar = fmaf(h, Urq[k], ar);
                    ah = fmaf(h, Uhq[k], ah);
                }
                if ((cu>>8) == q) hp = hb[(cu&255)*64 + lane];
                if (q<3){
                    wait_vm();
                    #pragma unroll
                    for (int s=0;s<8;s++) ((float4*)hs[(q+1)&1])[s*512 + tid] = sv[s];
                }
                __syncthreads();
            }
        }
        float z  = fsig_(xz + az + bz);
        float r  = fsig_(xr + ar + br);
        float hh = ftanh_(xh + r*(ah + bh));
        float hnew = z*hp + (1.f - z)*hh;
        st_dev4(hT + (size_t)(cur^1)*65536 + cu*64 + lane, hnew);   // coalesced fp32 publish
        hpe[((size_t)lane*TT + t)*HH + cu] = __float2half_rn(hnew); // fp16 attention stream (plain)
        gridbar(bar + (size_t)t*256, sub, 128);
    }
}

// ---------------- persistent decoder: 256 WGs x 512 thr (byte-identical to round 15) ----------------
__global__ __launch_bounds__(512) void k_dec(const __half* __restrict__ hpe,
                                             const float* __restrict__ Ut,
                                             const float* __restrict__ b1,
                                             const float* __restrict__ Edec,
                                             const float* __restrict__ scale,
                                             const float* __restrict__ fcW,
                                             const float* __restrict__ fcb,
                                             float* __restrict__ hdT,
                                             float* __restrict__ hdl,
                                             float* __restrict__ out,
                                             int* __restrict__ idx_t,
                                             int* __restrict__ bar,
                                             int* __restrict__ flagidx){
    __shared__ float hs[2][16384];
    __shared__ float ctxs[4][1024];
    __shared__ float edl[4][3][28];
    __shared__ float trs[256];
    __shared__ float m_s[4], S_s[4];
    __shared__ int c_a, c_fc, go, cstg;
    int tid = threadIdx.x, wg = blockIdx.x;
    if (tid == 0){ c_a=0; c_fc=0; go=0; cstg=0; }
    __syncthreads();

    if (tid < 256){
        // ============ matmul role ============
        int lane = tid & 63;
        int sub = wg & 15;
        int wv = tid >> 6;
        int cu = __builtin_amdgcn_readfirstlane(wg*4 + wv);
        const float* Uz = Ut + (size_t)cu*HH;
        const float* Ur = Uz + (size_t)HH*HH;
        const float* Uh = Ur + (size_t)HH*HH;
        float bz = b1[cu], br = b1[cu+HH], bh = b1[cu+2*HH];
        for (int tq = lane; tq < 84; tq += 64){
            int g = tq / 28, v = tq - g*28;
            edl[wv][g][v] = Edec[(size_t)v*H3 + cu + g*HH];
        }
        int stgt = 0;
        for (int i=0; i<TT; ++i){
            int cur = i & 1;
            float az=0.f, ar=0.f, ah=0.f, hp=0.f;
            if (i > 0){
                const float* gq = hdT + (size_t)cur*65536;
                float4 sv[16];
                #pragma unroll
                for (int s=0;s<16;s++) sv[s] = ld_dev16(gq + 4*(size_t)(s*256 + tid));
                wait_vm();
                #pragma unroll
                for (int s=0;s<16;s++) ((float4*)hs[0])[s*256 + tid] = sv[s];
                wbar4(&cstg, stgt += 4);
                for (int q=0;q<4;++q){
                    if (q<3){
                        #pragma unroll
                        for (int s=0;s<16;s++) sv[s] = ld_dev16(gq + (size_t)(q+1)*16384 + 4*(size_t)(s*256 + tid));
                    }
                    const float* hb = hs[q&1];
                    const float* Uzq = Uz + q*256;
                    const float* Urq = Ur + q*256;
                    const float* Uhq = Uh + q*256;
                    #pragma unroll 8
                    for (int k=0;k<256;++k){
                        float h = hb[k*64 + lane];
                        az = fmaf(h, Uzq[k], az);
                        ar = fmaf(h, Urq[k], ar);
                        ah = fmaf(h, Uhq[k], ah);
                    }
                    if ((cu>>8) == q) hp = hb[(cu&255)*64 + lane];
                    if (q<3){
                        wait_vm();
                        #pragma unroll
                        for (int s=0;s<16;s++) ((float4*)hs[(q+1)&1])[s*256 + tid] = sv[s];
                    }
                    wbar4(&cstg, stgt += 4);
                }
            }
            // wait for idx(i): single poller + LDS broadcast
            if (tid == 0){
                unsigned gy = 0; int s;
                do {
                    s = 0;
                    #pragma unroll
                    for (int c=0;c<8;c++) s += __hip_atomic_load(flagidx + (size_t)i*128 + c*16, __ATOMIC_RELAXED, AGENT);
                    if (s < 64){ if (++gy > SPIN_CAP) break; __builtin_amdgcn_s_sleep(4); }
                } while (s < 64);
                __hip_atomic_store(&go, i+1, __ATOMIC_RELAXED, WGRP);
            }
            { unsigned gy=0; while (__hip_atomic_load(&go, __ATOMIC_RELAXED, WGRP) < i+1){ if (++gy > SPIN_CAP) break; } }
            asm volatile("" ::: "memory");
            int mi_raw = ld_dev4i(idx_t + (size_t)i*64 + lane);
            wait_vm();
            unsigned mi = (unsigned)mi_raw;
            if (mi > 27u) mi = 0;
            float xz = edl[wv][0][mi];
            float xr = edl[wv][1][mi];
            float xh = edl[wv][2][mi];
            float z  = fsig_(xz + az + bz);
            float r  = fsig_(xr + ar + br);
            float hh = ftanh_(xh + r*(ah + bh));
            float hnew = z*hp + (1.f - z)*hh;
            st_dev4(hdT + (size_t)(cur^1)*65536 + cu*64 + lane, hnew);
            trs[lane*4 + wv] = hnew;
            wbar4(&cstg, stgt += 4);
            if (wv == 0){
                f32x4 h4 = *(const f32x4*)(trs + lane*4);
                st_dev16(hdl + (size_t)(cur^1)*65536 + (size_t)lane*HH + wg*4, h4);
            }
            gridbar(bar + (size_t)i*256, sub, 256);
        }
    } else if (wg < 64){
        // ============ attention team for batch b = wg ============
        int t2 = tid - 256;
        int w = t2 >> 6, lane = t2 & 63, b = wg;
        float sc[16];
        #pragma unroll
        for (int s4=0;s4<4;s4++){
            float4 v = *(const float4*)(scale + lane*16 + s4*4);
            sc[s4*4+0]=v.x; sc[s4*4+1]=v.y; sc[s4*4+2]=v.z; sc[s4*4+3]=v.w;
        }
        int j0 = w*25;
        const __half* hpb = hpe + ((size_t)b*TT + j0)*HH + lane*16;
        for (int i=0; i<TT; ++i){
            float q[16];
            if (i == 0){
                #pragma unroll
                for (int d=0;d<16;d++) q[d]=0.f;
            } else {
                const float* hq = hdl + (size_t)(i&1)*65536 + (size_t)b*HH + lane*16;
                float4 q0 = ld_dev16(hq), q1 = ld_dev16(hq+4), q2 = ld_dev16(hq+8), q3 = ld_dev16(hq+12);
                wait_vm();
                q[0]=q0.x;q[1]=q0.y;q[2]=q0.z;q[3]=q0.w;
                q[4]=q1.x;q[5]=q1.y;q[6]=q1.z;q[7]=q1.w;
                q[8]=q2.x;q[9]=q2.y;q[10]=q2.z;q[11]=q2.w;
                q[12]=q3.x;q[13]=q3.y;q[14]=q3.z;q[15]=q3.w;
            }
            if (w == 0){
                if (i > 0){
                    float acc[NOUT];
                    #pragma unroll
                    for (int o=0;o<NOUT;o++) acc[o]=0.f;
                    float cv[16];
                    #pragma unroll
                    for (int s4=0;s4<4;s4++){
                        float4 c0 = ((const float4*)ctxs[0])[lane*4+s4];
                        float4 c1 = ((const float4*)ctxs[1])[lane*4+s4];
                        float4 c2 = ((const float4*)ctxs[2])[lane*4+s4];
                        float4 c3 = ((const float4*)ctxs[3])[lane*4+s4];
                        cv[s4*4+0]=c0.x+c1.x+c2.x+c3.x;
                        cv[s4*4+1]=c0.y+c1.y+c2.y+c3.y;
                        cv[s4*4+2]=c0.z+c1.z+c2.z+c3.z;
                        cv[s4*4+3]=c0.w+c1.w+c2.w+c3.w;
                    }
                    #pragma unroll
                    for (int dd=0;dd<16;++dd){
                        int d = lane*16 + dd;
                        const float* w0p = fcW + (size_t)d*NOUT;
                        const float* w1p = fcW + (size_t)(d+HH)*NOUT;
                        float hv=q[dd], cvv=cv[dd];
                        #pragma unroll
                        for (int o=0;o<NOUT;o++) acc[o] = fmaf(hv, w0p[o], fmaf(cvv, w1p[o], acc[o]));
                    }
                    #pragma unroll
                    for (int o=0;o<NOUT;o++){
                        #pragma unroll
                        for (int m=1;m<64;m<<=1) acc[o] += __shfl_xor(acc[o], m);
                    }
                    float bv=-3.0e38f; int bi=0;
                    #pragma unroll
                    for (int o=0;o<NOUT;o++){
                        float p = acc[o] + fcb[o];
                        acc[o] = p;
                        if (p > bv){ bv = p; bi = o; }
                    }
                    float vout = 0.f;
                    #pragma unroll
                    for (int o=0;o<NOUT;o++) if (lane == o) vout = acc[o];
                    if (lane < NOUT) out[((size_t)b*TT + (i-1))*NOUT + lane] = vout;
                    if (lane == 0){
                        __hip_atomic_store(idx_t + (size_t)i*64 + b, bi, __ATOMIC_RELAXED, AGENT);
                        asm volatile("s_waitcnt vmcnt(0)" ::: "memory");
                    }
                }
                if (lane == 0){
                    __hip_atomic_fetch_add(flagidx + (size_t)i*128 + (b&7)*16, 1, __ATOMIC_RELAXED, AGENT);
                    __hip_atomic_fetch_add(&c_fc, 1, __ATOMIC_RELAXED, WGRP);
                }
            }
            // ---- online-softmax, hpe (fp16, plain loads) read once, next-row prefetch ----
            float m = -3.0e38f, S = 0.f;
            float a[16];
            #pragma unroll
            for (int d=0;d<16;d++) a[d]=0.f;
            u32x4 n0 = *(const u32x4*)(hpb);
            u32x4 n1 = *(const u32x4*)(hpb + 8);
            for (int jj=0;jj<25;jj++){
                u32x4 v0=n0, v1=n1;
                if (jj < 24){
                    const __half* hpn = hpb + (size_t)(jj+1)*HH;
                    n0 = *(const u32x4*)(hpn);
                    n1 = *(const u32x4*)(hpn + 8);
                }
                float va[16];
                float2 f;
                f=h2f(v0.x); va[0]=f.x; va[1]=f.y;  f=h2f(v0.y); va[2]=f.x; va[3]=f.y;
                f=h2f(v0.z); va[4]=f.x; va[5]=f.y;  f=h2f(v0.w); va[6]=f.x; va[7]=f.y;
                f=h2f(v1.x); va[8]=f.x; va[9]=f.y;  f=h2f(v1.y); va[10]=f.x; va[11]=f.y;
                f=h2f(v1.z); va[12]=f.x; va[13]=f.y; f=h2f(v1.w); va[14]=f.x; va[15]=f.y;
                float s = 0.f;
                #pragma unroll
                for (int d=0;d<16;d++) s += sc[d]*ftanh_(q[d] + va[d]);
                #pragma unroll
                for (int mm=1;mm<64;mm<<=1) s += __shfl_xor(s, mm);
                float mn = fmaxf(m, s);
                float fold = __expf(m - mn);
                float e = __expf(s - mn);
                S = S*fold + e;
                #pragma unroll
                for (int d=0;d<16;d++) a[d] = a[d]*fold + e*va[d];
                m = mn;
            }
            if (lane == 0){ m_s[w] = m; S_s[w] = S; }
            asm volatile("s_waitcnt lgkmcnt(0)" ::: "memory");
            if (lane == 0) __hip_atomic_fetch_add(&c_a, 1, __ATOMIC_RELAXED, WGRP);
            { unsigned gy=0; while (__hip_atomic_load(&c_a, __ATOMIC_RELAXED, WGRP) < 4*(i+1)){ if (++gy > SPIN_CAP) break; } }
            asm volatile("" ::: "memory");
            float M = fmaxf(fmaxf(m_s[0],m_s[1]), fmaxf(m_s[2],m_s[3]));
            float St = S_s[0]*__expf(m_s[0]-M) + S_s[1]*__expf(m_s[1]-M)
                     + S_s[2]*__expf(m_s[2]-M) + S_s[3]*__expf(m_s[3]-M);
            float g = __expf(m - M) * frcp_(St);
            { unsigned gy=0; while (__hip_atomic_load(&c_fc, __ATOMIC_RELAXED, WGRP) < i+1){ if (++gy > SPIN_CAP) break; } }
            asm volatile("" ::: "memory");
            #pragma unroll
            for (int s4=0;s4<4;s4++){
                float4 o4;
                o4.x=a[s4*4+0]*g; o4.y=a[s4*4+1]*g;
                o4.z=a[s4*4+2]*g; o4.w=a[s4*4+3]*g;
                ((float4*)ctxs[w])[lane*4 + s4] = o4;
            }
            gridbar(bar + (size_t)i*256, wg & 15, 256);
        }
        // epilogue: p(99) = [hd(100), ctx(99)] @ fc ; hd(100) is in hdl slot 0
        if (w == 0){
            const float* hq = hdl + (size_t)b*HH + lane*16;
            float4 q0 = ld_dev16(hq), q1 = ld_dev16(hq+4), q2 = ld_dev16(hq+8), q3 = ld_dev16(hq+12);
            wait_vm();
            float q[16];
            q[0]=q0.x;q[1]=q0.y;q[2]=q0.z;q[3]=q0.w;
            q[4]=q1.x;q[5]=q1.y;q[6]=q1.z;q[7]=q1.w;
            q[8]=q2.x;q[9]=q2.y;q[10]=q2.z;q[11]=q2.w;
            q[12]=q3.x;q[13]=q3.y;q[14]=q3.z;q[15]=q3.w;
            float acc[NOUT];
            #pragma unroll
            for (int o=0;o<NOUT;o++) acc[o]=0.f;
            float cv[16];
            #pragma unroll
            for (int s4=0;s4<4;s4++){
                float4 c0 = ((const float4*)ctxs[0])[lane*4+s4];
                float4 c1 = ((const float4*)ctxs[1])[lane*4+s4];
                float4 c2 = ((const float4*)ctxs[2])[lane*4+s4];
                float4 c3 = ((const float4*)ctxs[3])[lane*4+s4];
                cv[s4*4+0]=c0.x+c1.x+c2.x+c3.x;
                cv[s4*4+1]=c0.y+c1.y+c2.y+c3.y;
                cv[s4*4+2]=c0.z+c1.z+c2.z+c3.z;
                cv[s4*4+3]=c0.w+c1.w+c2.w+c3.w;
            }
            #pragma unroll
            for (int dd=0;dd<16;++dd){
                int d = lane*16 + dd;
                const float* w0p = fcW + (size_t)d*NOUT;
                const float* w1p = fcW + (size_t)(d+HH)*NOUT;
                float hv=q[dd], cvv=cv[dd];
                #pragma unroll
                for (int o=0;o<NOUT;o++) acc[o] = fmaf(hv, w0p[o], fmaf(cvv, w1p[o], acc[o]));
            }
            #pragma unroll
            for (int o=0;o<NOUT;o++){
                #pragma unroll
                for (int m=1;m<64;m<<=1) acc[o] += __shfl_xor(acc[o], m);
            }
            float vout = 0.f;
            #pragma unroll
            for (int o=0;o<NOUT;o++) if (lane == o) vout = acc[o] + fcb[o];
            if (lane < NOUT) out[((size_t)b*TT + 99)*NOUT + lane] = vout;
        }
    } else {
        for (int i=0;i<TT;++i) gridbar(bar + (size_t)i*256, wg & 15, 256);
    }
}

extern "C" void kernel_launch(void* const* d_in, const int* in_sizes, int n_in,
                              void* d_out, int out_size, void* d_ws, size_t ws_size,
                              hipStream_t stream){
    (void)in_sizes; (void)n_in; (void)out_size; (void)ws_size;
    const float* x     = (const float*)d_in[0];
    const float* encW  = (const float*)d_in[1];
    const float* encU  = (const float*)d_in[2];
    const float* encb  = (const float*)d_in[3];
    const float* scale = (const float*)d_in[4];
    const float* emb   = (const float*)d_in[5];
    const float* decW  = (const float*)d_in[6];
    const float* decU  = (const float*)d_in[7];
    const float* decb  = (const float*)d_in[8];
    const float* fcW   = (const float*)d_in[9];
    const float* fcb   = (const float*)d_in[10];
    float* out = (float*)d_out;
    float* ws  = (float*)d_ws;

    // same float-offset map as rounds 8-15 (hpe used as half within its region)
    float* MXT   = ws;                        // 19,660,800 (encoder phase only)
    float* hdT   = MXT;                       // dec overlay: 2*65,536 ping-pong [k][b] (fp32)
    float* hdl   = MXT + 131072;              // dec overlay: 2*65,536 ping-pong [b][k] (fp32)
    float* encUt = MXT   + 19660800;          // 3,145,728
    float* decUt = encUt + 3145728;           // 3,145,728
    float* hpeF  = decUt + 3145728;           // region 6,553,600 floats; used as halves
    __half* hpe  = (__half*)hpeF;             // 6,553,600 halves
    float* Edec  = hpeF  + 6553600;           // 86,016
    float* hT    = Edec  + 86016;             // 2*65,536 ping-pong [k][b] (encoder, fp32)
    int*   ib    = (int*)(hT + 131072);
    int*   bar_enc = ib;                      // 100*256
    int*   bar_dec = ib + 25600;              // 100*256
    int*   flagidx = ib + 51200;              // 100*128
    int*   idx_t   = ib + 64000;              // 100*64   (total 70,400 ints)

    const float* encb1 = encb + H3;
    const float* decb1 = decb + H3;

    k_init<<<276,256,0,stream>>>(ib, 70400);
    k_transpose<<<dim3(96,32,2),256,0,stream>>>(encU, decU, encUt, decUt);
    k_edec<<<336,256,0,stream>>>(emb, decW, decb, Edec);
    k_mxgemm<<<dim3(48,100),256,0,stream>>>(x, encW, encb, MXT);
    k_enc<<<128,512,0,stream>>>(MXT, encUt, encb1, hpe, hT, bar_enc);
    k_dec<<<256,512,0,stream>>>(hpe, decUt, decb1, Edec, scale, fcW, fcb,
                                hdT, hdl, out, idx_t, bar_dec, flagidx);
}